// Round 19
// baseline (568.728 us; speedup 1.0000x reference)
//
#include <hip/hip_runtime.h>
#include <hip/hip_bf16.h>

#define NA_ 4096
#define NB_ 4096
#define NN_ 8192            // total nodes
#define EE_ 131072          // edges per direction
#define NE_ (2*EE_ + NN_)   // homogeneous edges incl. self loops = 270336
#define HH_ 512
#define NEG_SLOPE_ 0.2f

typedef __attribute__((ext_vector_type(4))) float f32x4;
typedef __attribute__((ext_vector_type(8))) short s16x8;

__device__ inline unsigned short f2bf(float v) {
    __hip_bfloat16 h = __float2bfloat16(v);
    return __builtin_bit_cast(unsigned short, h);
}
__device__ inline float bf2f(unsigned short u) {
    return __uint_as_float(((unsigned)u) << 16);
}

#define GLOAD16(gsrc, ldst)                                                    \
    __builtin_amdgcn_global_load_lds(                                          \
        (const __attribute__((address_space(1))) unsigned int*)(gsrc),         \
        (__attribute__((address_space(3))) unsigned int*)(ldst), 16, 0, 0)

// ---------------- homogeneous edge id -> (src, dst) ------------------------
__device__ inline void edge_sd(int i, const int* __restrict__ eAB,
                               const int* __restrict__ eBA, int& s, int& d) {
    if (i < EE_)            { s = eAB[i];            d = eAB[EE_ + i] + NA_; }
    else if (i < 2 * EE_)   { int j = i - EE_; s = eBA[j] + NA_; d = eBA[EE_ + j]; }
    else                    { s = i - 2 * EE_;       d = s; }
}

// ---------------- batched f32 -> bf16 (optionally split hi/lo) casts --------
struct CvtJob { const float* s; unsigned short* hi; unsigned short* lo; int n4; };
struct CvtJobs { CvtJob j[10]; };

__global__ __launch_bounds__(256) void cvt_all_k(CvtJobs jobs) {
    const CvtJob jb = jobs.j[blockIdx.y];
    int i = blockIdx.x * 256 + threadIdx.x;
    if (i >= jb.n4) return;
    float4 v = ((const float4*)jb.s)[i];
    ushort4 h;
    h.x = f2bf(v.x); h.y = f2bf(v.y); h.z = f2bf(v.z); h.w = f2bf(v.w);
    ((ushort4*)jb.hi)[i] = h;
    if (jb.lo) {
        ushort4 l;
        l.x = f2bf(v.x - bf2f(h.x));
        l.y = f2bf(v.y - bf2f(h.y));
        l.z = f2bf(v.z - bf2f(h.z));
        l.w = f2bf(v.w - bf2f(h.w));
        ((ushort4*)jb.lo)[i] = l;
    }
}

// ---------------- MFMA bf16 GEMM: C[M,N] = A @ B^T (+bias) -----------------
template<int BM, int BN, bool BIAS, typename OutT>
__global__ __launch_bounds__(256) void mgemm_k(
    const unsigned short* __restrict__ A, const unsigned short* __restrict__ B,
    const float* __restrict__ bias, OutT* __restrict__ C,
    int K, int lda, int ldb, int ldc)
{
    constexpr int BK = 32;
    constexpr int WM = BM / 2, WN = BN / 2;
    constexpr int AM = WM / 16, AN = WN / 16;
    constexpr int AISS = BM * 4 / 256, BISS = BN * 4 / 256;
    __shared__ unsigned short sA[BM * BK];
    __shared__ unsigned short sB[BN * BK];
    const int t = threadIdx.x, lane = t & 63, w = t >> 6;
    const int wr = w >> 1, wc = w & 1;
    const int fr = lane & 15, fq = lane >> 4;
    const int bm = blockIdx.y * BM, bn = blockIdx.x * BN;

    f32x4 acc[AM][AN];
    #pragma unroll
    for (int m = 0; m < AM; m++)
        #pragma unroll
        for (int n = 0; n < AN; n++)
            #pragma unroll
            for (int r = 0; r < 4; r++) acc[m][n][r] = 0.f;

    for (int k0 = 0; k0 < K; k0 += BK) {
        __syncthreads();
        #pragma unroll
        for (int i = 0; i < AISS; i++) {
            int slot = i * 256 + t;
            GLOAD16(A + (size_t)(bm + (slot >> 2)) * lda + k0 + (slot & 3) * 8,
                    sA + (i * 256 + w * 64) * 8);
        }
        #pragma unroll
        for (int i = 0; i < BISS; i++) {
            int slot = i * 256 + t;
            GLOAD16(B + (size_t)(bn + (slot >> 2)) * ldb + k0 + (slot & 3) * 8,
                    sB + (i * 256 + w * 64) * 8);
        }
        __syncthreads();
        s16x8 a[AM], b[AN];
        #pragma unroll
        for (int m = 0; m < AM; m++)
            a[m] = *(const s16x8*)&sA[(wr * WM + m * 16 + fr) * BK + fq * 8];
        #pragma unroll
        for (int n = 0; n < AN; n++)
            b[n] = *(const s16x8*)&sB[(wc * WN + n * 16 + fr) * BK + fq * 8];
        #pragma unroll
        for (int m = 0; m < AM; m++)
            #pragma unroll
            for (int n = 0; n < AN; n++)
                acc[m][n] = __builtin_amdgcn_mfma_f32_16x16x32_bf16(a[m], b[n], acc[m][n], 0, 0, 0);
    }

    #pragma unroll
    for (int m = 0; m < AM; m++) {
        const int row = bm + wr * WM + m * 16 + fq * 4;
        #pragma unroll
        for (int n = 0; n < AN; n++) {
            const int col = bn + wc * WN + n * 16 + fr;
            const float bv = BIAS ? bias[col] : 0.f;
            #pragma unroll
            for (int r = 0; r < 4; r++) {
                float v = acc[m][n][r] + bv;
                if constexpr (sizeof(OutT) == 2)
                    C[(size_t)(row + r) * ldc + col] = (OutT)f2bf(v);
                else
                    C[(size_t)(row + r) * ldc + col] = v;
            }
        }
    }
}

// ---------------- QK^T: 128x128 tile, 4 waves, dbuf BK=32 (m97 density) -----
// grid (64,16) = 1024 blocks -> 4+ blocks/CU co-resident; barrier drains
// overlap across blocks (m114). q pre-scaled by scale*log2e; P = 2^(q.k).
__global__ __launch_bounds__(256) void mgemm_qk_k(
    const unsigned short* __restrict__ A, const unsigned short* __restrict__ B,
    unsigned short* __restrict__ C, float* __restrict__ denom)
{
    constexpr int BK = 32;
    __shared__ unsigned short smem[16384];    // 32KB: 2 bufs x (A 8KB | B 8KB)
    const int t = threadIdx.x, lane = t & 63, w = t >> 6;
    const int wr = w >> 1, wc = w & 1;
    const int fr = lane & 15, fq = lane >> 4;
    const int bm = blockIdx.y * 128, bn = blockIdx.x * 128;

    f32x4 acc[4][4];
    #pragma unroll
    for (int m = 0; m < 4; m++)
        #pragma unroll
        for (int n = 0; n < 4; n++)
            #pragma unroll
            for (int r = 0; r < 4; r++) acc[m][n][r] = 0.f;

    auto stage = [&](int buf, int k0) {
        unsigned short* dA = smem + buf * 8192;
        unsigned short* dB = dA + 4096;
        #pragma unroll
        for (int i = 0; i < 2; i++) {
            int s = i * 256 + t;              // 512 slots = 128 rows x 4 cc
            int row = s >> 2, cc = s & 3;
            int gc = k0 + ((cc ^ (row & 3)) << 3);
            GLOAD16(A + (size_t)(bm + row) * 512 + gc, dA + (i * 256 + w * 64) * 8);
            GLOAD16(B + (size_t)(bn + row) * 512 + gc, dB + (i * 256 + w * 64) * 8);
        }
    };

    stage(0, 0);
    asm volatile("s_waitcnt vmcnt(0)" ::: "memory");
    __builtin_amdgcn_s_barrier();
    int cur = 0;
    for (int k0 = 0; k0 < 512; k0 += BK) {
        if (k0 + BK < 512) stage(cur ^ 1, k0 + BK);
        const unsigned short* rA = smem + cur * 8192;
        const unsigned short* rB = rA + 4096;
        s16x8 a[4], b[4];
        #pragma unroll
        for (int m = 0; m < 4; m++) {
            int row = wr * 64 + m * 16 + fr;
            a[m] = *(const s16x8*)&rA[row * BK + ((fq ^ (row & 3)) << 3)];
        }
        #pragma unroll
        for (int n = 0; n < 4; n++) {
            int row = wc * 64 + n * 16 + fr;
            b[n] = *(const s16x8*)&rB[row * BK + ((fq ^ (row & 3)) << 3)];
        }
        __builtin_amdgcn_s_setprio(1);
        #pragma unroll
        for (int m = 0; m < 4; m++)
            #pragma unroll
            for (int n = 0; n < 4; n++)
                acc[m][n] = __builtin_amdgcn_mfma_f32_16x16x32_bf16(a[m], b[n], acc[m][n], 0, 0, 0);
        __builtin_amdgcn_s_setprio(0);
        asm volatile("s_waitcnt vmcnt(0)" ::: "memory");
        __builtin_amdgcn_s_barrier();
        cur ^= 1;
    }

    // epilogue: exp2 + row-sum (atomic) + direct stores (32B runs)
    #pragma unroll
    for (int m = 0; m < 4; m++) {
        #pragma unroll
        for (int r = 0; r < 4; r++) {
            const int row = bm + wr * 64 + m * 16 + fq * 4 + r;   // chunk-local
            float rsum = 0.f;
            #pragma unroll
            for (int n = 0; n < 4; n++) {
                float p = exp2f(acc[m][n][r]);
                rsum += p;
                C[(size_t)row * 8192 + bn + wc * 64 + n * 16 + fr] = f2bf(p);
            }
            rsum += __shfl_xor(rsum, 1);
            rsum += __shfl_xor(rsum, 2);
            rsum += __shfl_xor(rsum, 4);
            rsum += __shfl_xor(rsum, 8);
            if (fr == 0) atomicAdd(&denom[row], rsum);
        }
    }
}

// ---------------- merged per-type input linear (A rows 0..4095, B rows 4096+)
template<bool SPLIT>
__global__ __launch_bounds__(256) void mgemm_in_k(
    const unsigned short* __restrict__ xA, const unsigned short* __restrict__ xB,
    const unsigned short* __restrict__ WA, const unsigned short* __restrict__ WB,
    const float* __restrict__ biasA, const float* __restrict__ biasB,
    unsigned short* __restrict__ o1, unsigned short* __restrict__ o2)
{
    constexpr int BK = 32;
    __shared__ unsigned short sA[128 * BK];
    __shared__ unsigned short sB[128 * BK];
    const int t = threadIdx.x, lane = t & 63, w = t >> 6;
    const int wr = w >> 1, wc = w & 1;
    const int fr = lane & 15, fq = lane >> 4;
    const int bm = blockIdx.y * 128, bn = blockIdx.x * 128;
    const bool isB = bm >= NA_;
    const unsigned short* A = isB ? xB : xA;
    const unsigned short* W = isB ? WB : WA;
    const float* bias = isB ? biasB : biasA;
    const int bml = bm - (isB ? NA_ : 0);

    f32x4 acc[4][4];
    #pragma unroll
    for (int m = 0; m < 4; m++)
        #pragma unroll
        for (int n = 0; n < 4; n++)
            #pragma unroll
            for (int r = 0; r < 4; r++) acc[m][n][r] = 0.f;

    for (int k0 = 0; k0 < 256; k0 += BK) {
        __syncthreads();
        #pragma unroll
        for (int i = 0; i < 2; i++) {
            int slot = i * 256 + t;
            GLOAD16(A + (size_t)(bml + (slot >> 2)) * 256 + k0 + (slot & 3) * 8,
                    sA + (i * 256 + w * 64) * 8);
            GLOAD16(W + (size_t)(bn + (slot >> 2)) * 256 + k0 + (slot & 3) * 8,
                    sB + (i * 256 + w * 64) * 8);
        }
        __syncthreads();
        s16x8 a[4], b[4];
        #pragma unroll
        for (int m = 0; m < 4; m++)
            a[m] = *(const s16x8*)&sA[(wr * 64 + m * 16 + fr) * BK + fq * 8];
        #pragma unroll
        for (int n = 0; n < 4; n++)
            b[n] = *(const s16x8*)&sB[(wc * 64 + n * 16 + fr) * BK + fq * 8];
        #pragma unroll
        for (int m = 0; m < 4; m++)
            #pragma unroll
            for (int n = 0; n < 4; n++)
                acc[m][n] = __builtin_amdgcn_mfma_f32_16x16x32_bf16(a[m], b[n], acc[m][n], 0, 0, 0);
    }

    #pragma unroll
    for (int m = 0; m < 4; m++) {
        const int row = bm + wr * 64 + m * 16 + fq * 4;
        #pragma unroll
        for (int n = 0; n < 4; n++) {
            const int col = bn + wc * 64 + n * 16 + fr;
            const float bv = bias[col];
            #pragma unroll
            for (int r = 0; r < 4; r++) {
                float v = acc[m][n][r] + bv;
                unsigned short hi = f2bf(v);
                o1[(size_t)(row + r) * 512 + col] = hi;
                if (SPLIT)
                    o2[(size_t)(row + r) * 512 + col] = f2bf(v - bf2f(hi));
            }
        }
    }
}

// ---------------- split-A MFMA GEMM (2 MFMA), dbuf pipeline + fused dots ----
__global__ __launch_bounds__(256) void mgemm3_k(
    const unsigned short* __restrict__ Ahi, const unsigned short* __restrict__ Alo,
    const unsigned short* __restrict__ Bhi,
    unsigned short* __restrict__ Cb, const float* __restrict__ a_src,
    const float* __restrict__ a_dst, float* __restrict__ as_,
    float* __restrict__ ad_, int K, int lda, int ldb)
{
    constexpr int BK = 32;
    __shared__ unsigned short smem[24576];    // 48KB: 2 bufs x (Ah|Al|Bh) x 8KB
    const int t = threadIdx.x, lane = t & 63, w = t >> 6;
    const int wr = w >> 1, wc = w & 1;
    const int fr = lane & 15, fq = lane >> 4;
    const int bm = blockIdx.y * 128, bn = blockIdx.x * 128;

    f32x4 acc[4][4];
    #pragma unroll
    for (int m = 0; m < 4; m++)
        #pragma unroll
        for (int n = 0; n < 4; n++)
            #pragma unroll
            for (int r = 0; r < 4; r++) acc[m][n][r] = 0.f;

    auto stage = [&](int buf, int k0) {
        unsigned short* dAh = smem + buf * 12288;
        unsigned short* dAl = dAh + 4096;
        unsigned short* dBh = dAh + 8192;
        #pragma unroll
        for (int i = 0; i < 2; i++) {
            int s = i * 256 + t;              // 512 slots = 128 rows x 4 cc
            int row = s >> 2, cc = s & 3;
            int gco = (cc ^ (row & 3)) << 3;
            size_t ga = (size_t)(bm + row) * lda + k0 + gco;
            size_t gb = (size_t)(bn + row) * ldb + k0 + gco;
            unsigned loff = (unsigned)(i * 256 + w * 64) * 8;
            GLOAD16(Ahi + ga, dAh + loff);
            GLOAD16(Alo + ga, dAl + loff);
            GLOAD16(Bhi + gb, dBh + loff);
        }
    };

    stage(0, 0);
    asm volatile("s_waitcnt vmcnt(0)" ::: "memory");
    __builtin_amdgcn_s_barrier();
    int cur = 0;
    for (int k0 = 0; k0 < K; k0 += BK) {
        if (k0 + BK < K) stage(cur ^ 1, k0 + BK);
        const unsigned short* rAh = smem + cur * 12288;
        const unsigned short* rAl = rAh + 4096;
        const unsigned short* rBh = rAh + 8192;
        s16x8 ah[4], al[4], bh[4];
        #pragma unroll
        for (int m = 0; m < 4; m++) {
            int row = wr * 64 + m * 16 + fr;
            int o = row * BK + ((fq ^ (row & 3)) << 3);
            ah[m] = *(const s16x8*)&rAh[o];
            al[m] = *(const s16x8*)&rAl[o];
        }
        #pragma unroll
        for (int n = 0; n < 4; n++) {
            int row = wc * 64 + n * 16 + fr;
            bh[n] = *(const s16x8*)&rBh[row * BK + ((fq ^ (row & 3)) << 3)];
        }
        __builtin_amdgcn_s_setprio(1);
        #pragma unroll
        for (int m = 0; m < 4; m++)
            #pragma unroll
            for (int n = 0; n < 4; n++) {
                acc[m][n] = __builtin_amdgcn_mfma_f32_16x16x32_bf16(ah[m], bh[n], acc[m][n], 0, 0, 0);
                acc[m][n] = __builtin_amdgcn_mfma_f32_16x16x32_bf16(al[m], bh[n], acc[m][n], 0, 0, 0);
            }
        __builtin_amdgcn_s_setprio(0);
        asm volatile("s_waitcnt vmcnt(0)" ::: "memory");
        __builtin_amdgcn_s_barrier();
        cur ^= 1;
    }

    float asv[4], adv[4];
    #pragma unroll
    for (int n = 0; n < 4; n++) {
        const int col = bn + wc * 64 + n * 16 + fr;
        asv[n] = a_src[col];
        adv[n] = a_dst[col];
    }

    #pragma unroll
    for (int m = 0; m < 4; m++) {
        const int row = bm + wr * 64 + m * 16 + fq * 4;
        #pragma unroll
        for (int r = 0; r < 4; r++) {
            float s1 = 0.f, s2 = 0.f;
            #pragma unroll
            for (int n = 0; n < 4; n++) {
                const int col = bn + wc * 64 + n * 16 + fr;
                float v = acc[m][n][r];
                Cb[(size_t)(row + r) * 512 + col] = f2bf(v);
                s1 = fmaf(v, asv[n], s1);
                s2 = fmaf(v, adv[n], s2);
            }
            s1 += __shfl_xor(s1, 1); s2 += __shfl_xor(s2, 1);
            s1 += __shfl_xor(s1, 2); s2 += __shfl_xor(s2, 2);
            s1 += __shfl_xor(s1, 4); s2 += __shfl_xor(s2, 4);
            s1 += __shfl_xor(s1, 8); s2 += __shfl_xor(s2, 8);
            if (fr == 0) {
                atomicAdd(&as_[row + r], s1);
                atomicAdd(&ad_[row + r], s2);
            }
        }
    }
}

// ---------------- PV split-K: dbuf BK=32 pipeline, XCD swizzle --------------
__global__ __launch_bounds__(256) void mgemm_pv_k(
    const unsigned short* __restrict__ A, const unsigned short* __restrict__ B,
    unsigned short* __restrict__ C, int kseg, size_t segstride)
{
    constexpr int BK = 32;
    __shared__ unsigned short smem[16384];    // 32KB: 2 bufs x (A 8KB | B 8KB)
    const int t = threadIdx.x, lane = t & 63, w = t >> 6;
    const int wr = w >> 1, wc = w & 1;
    const int fr = lane & 15, fq = lane >> 4;
    const int L  = blockIdx.x + (blockIdx.y << 2) + (blockIdx.z << 6);
    const int xs = L >> 7;
    const int ys = (L & 127) & 15;
    const int zs = (L & 127) >> 4;
    const int bm = ys * 128, bn = xs * 128;
    const int kofs = zs * kseg;

    f32x4 acc[4][4];
    #pragma unroll
    for (int m = 0; m < 4; m++)
        #pragma unroll
        for (int n = 0; n < 4; n++)
            #pragma unroll
            for (int r = 0; r < 4; r++) acc[m][n][r] = 0.f;

    auto stage = [&](int buf, int k0) {
        unsigned short* dA = smem + buf * 8192;
        unsigned short* dB = dA + 4096;
        #pragma unroll
        for (int i = 0; i < 2; i++) {
            int s = i * 256 + t;              // 512 slots = 128 rows x 4 cc
            int row = s >> 2, cc = s & 3;
            int gc = kofs + k0 + ((cc ^ (row & 3)) << 3);
            GLOAD16(A + (size_t)(bm + row) * 8192 + gc, dA + (i * 256 + w * 64) * 8);
            GLOAD16(B + (size_t)(bn + row) * 8192 + gc, dB + (i * 256 + w * 64) * 8);
        }
    };

    stage(0, 0);
    asm volatile("s_waitcnt vmcnt(0)" ::: "memory");
    __builtin_amdgcn_s_barrier();
    int cur = 0;
    for (int k0 = 0; k0 < kseg; k0 += BK) {
        if (k0 + BK < kseg) stage(cur ^ 1, k0 + BK);
        const unsigned short* rA = smem + cur * 8192;
        const unsigned short* rB = rA + 4096;
        s16x8 a[4], b[4];
        #pragma unroll
        for (int m = 0; m < 4; m++) {
            int row = wr * 64 + m * 16 + fr;
            a[m] = *(const s16x8*)&rA[row * BK + ((fq ^ (row & 3)) << 3)];
        }
        #pragma unroll
        for (int n = 0; n < 4; n++) {
            int row = wc * 64 + n * 16 + fr;
            b[n] = *(const s16x8*)&rB[row * BK + ((fq ^ (row & 3)) << 3)];
        }
        __builtin_amdgcn_s_setprio(1);
        #pragma unroll
        for (int m = 0; m < 4; m++)
            #pragma unroll
            for (int n = 0; n < 4; n++)
                acc[m][n] = __builtin_amdgcn_mfma_f32_16x16x32_bf16(a[m], b[n], acc[m][n], 0, 0, 0);
        __builtin_amdgcn_s_setprio(0);
        asm volatile("s_waitcnt vmcnt(0)" ::: "memory");
        __builtin_amdgcn_s_barrier();
        cur ^= 1;
    }

    unsigned short* Cz = C + (size_t)zs * segstride;
    #pragma unroll
    for (int m = 0; m < 4; m++) {
        const int row = bm + wr * 64 + m * 16 + fq * 4;
        #pragma unroll
        for (int n = 0; n < 4; n++) {
            const int col = bn + wc * 64 + n * 16 + fr;
            #pragma unroll
            for (int r = 0; r < 4; r++)
                Cz[(size_t)(row + r) * 512 + col] = f2bf(acc[m][n][r]);
        }
    }
}

// ---------------- reduce bf16 split-K partials, divide by denom -> bf16 ----
__global__ __launch_bounds__(256) void radd_k(const unsigned short* __restrict__ src,
                                              unsigned short* __restrict__ dst,
                                              const float* __restrict__ dn,
                                              int n8, int segs, size_t stride8) {
    int i = blockIdx.x * 256 + threadIdx.x;
    if (i >= n8) return;
    float acc[8] = {0,0,0,0,0,0,0,0};
    for (int s = 0; s < segs; s++) {
        s16x8 v = ((const s16x8*)src)[i + s * stride8];
        #pragma unroll
        for (int j = 0; j < 8; j++) acc[j] += bf2f((unsigned short)v[j]);
    }
    const float rd = 1.0f / dn[i >> 6];    // 64 groups of 8 per 512-col row
    s16x8 o;
    #pragma unroll
    for (int j = 0; j < 8; j++) o[j] = (short)f2bf(acc[j] * rd);
    ((s16x8*)dst)[i] = o;
}

// ---------------- qkv MFMA GEMM with split epilogue (scale folded into q) ---
__global__ __launch_bounds__(256) void mgemm_qkv_k(
    const unsigned short* __restrict__ A, const unsigned short* __restrict__ B,
    const float* __restrict__ bias, float scale,
    unsigned short* __restrict__ qb, unsigned short* __restrict__ kb,
    unsigned short* __restrict__ vb)
{
    constexpr int BM = 128, BN = 128, BK = 32;
    __shared__ unsigned short sA[BM * BK];
    __shared__ unsigned short sB[BN * BK];
    const int t = threadIdx.x, lane = t & 63, w = t >> 6;
    const int wr = w >> 1, wc = w & 1;
    const int fr = lane & 15, fq = lane >> 4;
    const int bm = blockIdx.y * BM, bn = blockIdx.x * BN;

    f32x4 acc[4][4];
    #pragma unroll
    for (int m = 0; m < 4; m++)
        #pragma unroll
        for (int n = 0; n < 4; n++)
            #pragma unroll
            for (int r = 0; r < 4; r++) acc[m][n][r] = 0.f;

    for (int k0 = 0; k0 < 512; k0 += BK) {
        __syncthreads();
        #pragma unroll
        for (int i = 0; i < 2; i++) {
            int slot = i * 256 + t;
            GLOAD16(A + (size_t)(bm + (slot >> 2)) * 512 + k0 + (slot & 3) * 8,
                    sA + (i * 256 + w * 64) * 8);
            GLOAD16(B + (size_t)(bn + (slot >> 2)) * 512 + k0 + (slot & 3) * 8,
                    sB + (i * 256 + w * 64) * 8);
        }
        __syncthreads();
        s16x8 a[4], b[4];
        #pragma unroll
        for (int m = 0; m < 4; m++)
            a[m] = *(const s16x8*)&sA[(wr * 64 + m * 16 + fr) * BK + fq * 8];
        #pragma unroll
        for (int n = 0; n < 4; n++)
            b[n] = *(const s16x8*)&sB[(wc * 64 + n * 16 + fr) * BK + fq * 8];
        #pragma unroll
        for (int m = 0; m < 4; m++)
            #pragma unroll
            for (int n = 0; n < 4; n++)
                acc[m][n] = __builtin_amdgcn_mfma_f32_16x16x32_bf16(a[m], b[n], acc[m][n], 0, 0, 0);
    }

    #pragma unroll
    for (int m = 0; m < 4; m++) {
        const int row = bm + wr * 64 + m * 16 + fq * 4;
        #pragma unroll
        for (int n = 0; n < 4; n++) {
            const int col = bn + wc * 64 + n * 16 + fr;
            const float bv = bias[col];
            #pragma unroll
            for (int r = 0; r < 4; r++) {
                float v = acc[m][n][r] + bv;
                if (col < 512)
                    qb[(size_t)(row + r) * 512 + col] = f2bf(v * scale);
                else if (col < 1024)
                    kb[(size_t)(row + r) * 512 + (col - 512)] = f2bf(v);
                else
                    vb[(size_t)(row + r) * 512 + (col - 1024)] = f2bf(v);
            }
        }
    }
}

// ---------------- bf16 transpose: vb[8192][512] -> vT[512][8192] ------------
__global__ __launch_bounds__(256) void trT_k(const unsigned short* __restrict__ vb,
                                             unsigned short* __restrict__ vT) {
    __shared__ unsigned short s[64][65];
    const int t = threadIdx.x;
    const int rowo = blockIdx.y * 64;
    const int colo = blockIdx.x * 64;
    {
        int r = t >> 2, cg = (t & 3) * 16;
        const s16x8* src = (const s16x8*)(vb + (size_t)(rowo + r) * 512 + colo + cg);
        s16x8 u0 = src[0], u1 = src[1];
        #pragma unroll
        for (int j = 0; j < 8; j++) {
            s[r][cg + j]     = (unsigned short)u0[j];
            s[r][cg + 8 + j] = (unsigned short)u1[j];
        }
    }
    __syncthreads();
    {
        int c = t >> 2, rg = (t & 3) * 16;
        s16x8 o0, o1;
        #pragma unroll
        for (int j = 0; j < 8; j++) {
            o0[j] = (short)s[rg + j][c];
            o1[j] = (short)s[rg + 8 + j][c];
        }
        s16x8* dst = (s16x8*)(vT + (size_t)(colo + c) * 8192 + rowo + rg);
        dst[0] = o0; dst[1] = o1;
    }
}

// ---------------- CSR build ------------------------------------------------
__global__ void count_deg_k(const int* eAB, const int* eBA, int* deg) {
    int i = blockIdx.x * 256 + threadIdx.x;
    if (i >= NE_) return;
    int s, d; edge_sd(i, eAB, eBA, s, d);
    atomicAdd(&deg[d], 1);
}

__global__ __launch_bounds__(256) void scan_k(const int* __restrict__ deg, int* rowstart) {
    __shared__ int part[256];
    int t = threadIdx.x;
    int base = t * 32;
    int loc[32]; int s = 0;
    #pragma unroll
    for (int j = 0; j < 32; j++) { loc[j] = s; s += deg[base + j]; }
    part[t] = s;
    __syncthreads();
    if (t == 0) {
        int a = 0;
        for (int i = 0; i < 256; i++) { int v = part[i]; part[i] = a; a += v; }
        rowstart[NN_] = a;
    }
    __syncthreads();
    int off = part[t];
    #pragma unroll
    for (int j = 0; j < 32; j++) rowstart[base + j] = off + loc[j];
}

__global__ void fill_csr_k(const int* eAB, const int* eBA,
                           const int* __restrict__ rowstart, int* cursor,
                           int* csr_src, int* pos) {
    int i = blockIdx.x * 256 + threadIdx.x;
    if (i >= NE_) return;
    int s, d; edge_sd(i, eAB, eBA, s, d);
    int p = atomicAdd(&cursor[d], 1);
    int slot = rowstart[d] + p;
    csr_src[slot] = s;
    pos[i] = slot;
}

// ---------------- fused GAT edge pass: e -> exp(e) scatter + denom ----------
__global__ void edge_fused_k(const int* eAB, const int* eBA,
                             const float* __restrict__ as_, const float* __restrict__ ad_,
                             const int* __restrict__ pos,
                             float* __restrict__ evs, float* __restrict__ denom) {
    int i = blockIdx.x * 256 + threadIdx.x;
    if (i >= NE_) return;
    int s, d; edge_sd(i, eAB, eBA, s, d);
    float e = as_[s] + ad_[d];
    e = (e >= 0.f) ? e : NEG_SLOPE_ * e;
    float ex = expf(e);
    evs[pos[i]] = ex;
    atomicAdd(&denom[d], ex);
}

// ---------------- GAT aggregation: streaming CSR, 2-edge unrolled -----------
template<bool SPLIT>
__global__ __launch_bounds__(256) void gat_agg_k(
    const int* __restrict__ rowstart, const int* __restrict__ csr_src,
    const float* __restrict__ evs, const float* __restrict__ denom,
    const unsigned short* __restrict__ hb, const float* __restrict__ bias,
    float* __restrict__ outF, int ldo,
    unsigned short* __restrict__ outHi, unsigned short* __restrict__ outLo)
{
    int wid  = (blockIdx.x * 256 + threadIdx.x) >> 6;
    int lane = threadIdx.x & 63;
    if (wid >= NN_) return;
    float acc[8] = {0.f,0.f,0.f,0.f,0.f,0.f,0.f,0.f};
    int beg = rowstart[wid], end = rowstart[wid + 1];
    float rden = 1.0f / denom[wid];
    int p = beg;
    for (; p + 1 < end; p += 2) {
        int s0 = csr_src[p], s1 = csr_src[p + 1];
        float al0 = evs[p] * rden, al1 = evs[p + 1] * rden;
        s16x8 h0 = *(const s16x8*)(hb + (size_t)s0 * HH_ + lane * 8);
        s16x8 h1 = *(const s16x8*)(hb + (size_t)s1 * HH_ + lane * 8);
        #pragma unroll
        for (int j = 0; j < 8; j++)
            acc[j] = fmaf(al1, bf2f((unsigned short)h1[j]),
                     fmaf(al0, bf2f((unsigned short)h0[j]), acc[j]));
    }
    if (p < end) {
        int s0 = csr_src[p];
        float al0 = evs[p] * rden;
        s16x8 h0 = *(const s16x8*)(hb + (size_t)s0 * HH_ + lane * 8);
        #pragma unroll
        for (int j = 0; j < 8; j++)
            acc[j] = fmaf(al0, bf2f((unsigned short)h0[j]), acc[j]);
    }
    #pragma unroll
    for (int j = 0; j < 8; j++) acc[j] += bias[lane * 8 + j];
    if (SPLIT) {
        s16x8 hi, lo;
        #pragma unroll
        for (int j = 0; j < 8; j++) {
            unsigned short h = f2bf(acc[j]);
            hi[j] = (short)h;
            lo[j] = (short)f2bf(acc[j] - bf2f(h));
        }
        *(s16x8*)(outHi + (size_t)wid * HH_ + lane * 8) = hi;
        *(s16x8*)(outLo + (size_t)wid * HH_ + lane * 8) = lo;
    } else {
        float* o = outF + (size_t)wid * ldo + lane * 8;
        *(float4*)(o)     = make_float4(acc[0], acc[1], acc[2], acc[3]);
        *(float4*)(o + 4) = make_float4(acc[4], acc[5], acc[6], acc[7]);
    }
}

// ===========================================================================
extern "C" void kernel_launch(void* const* d_in, const int* in_sizes, int n_in,
                              void* d_out, int out_size, void* d_ws, size_t ws_size,
                              hipStream_t stream)
{
    const float* x_A    = (const float*)d_in[0];
    const float* x_B    = (const float*)d_in[1];
    const int*   eAB    = (const int*)d_in[2];
    const int*   eBA    = (const int*)d_in[3];
    const float* W_inA  = (const float*)d_in[4];  const float* b_inA  = (const float*)d_in[5];
    const float* W_inB  = (const float*)d_in[6];  const float* b_inB  = (const float*)d_in[7];
    const float* W_in2A = (const float*)d_in[8];  const float* b_in2A = (const float*)d_in[9];
    const float* W_in2B = (const float*)d_in[10]; const float* b_in2B = (const float*)d_in[11];
    const float* Wg1    = (const float*)d_in[12]; const float* a_src1 = (const float*)d_in[13];
    const float* a_dst1 = (const float*)d_in[14]; const float* bg1    = (const float*)d_in[15];
    const float* Wg2    = (const float*)d_in[16]; const float* a_src2 = (const float*)d_in[17];
    const float* a_dst2 = (const float*)d_in[18]; const float* bg2    = (const float*)d_in[19];
    const float* Wqkv   = (const float*)d_in[20]; const float* bqkv   = (const float*)d_in[21];
    const float* Wo     = (const float*)d_in[22]; const float* bo     = (const float*)d_in[23];

    float* out = (float*)d_out;

    char* base = (char*)d_ws;
    size_t off = 0;
    auto alloc = [&](size_t nb) -> char* {
        char* p = base + off;
        off = (off + nb + 255) & ~(size_t)255;
        return p;
    };

    // bufA and bufB MUST be adjacent: Sb (32MB) spans both during attention.
    float*          bufA  = (float*)alloc((size_t)NN_ * 512 * 4);
    float*          bufB  = (float*)alloc((size_t)NN_ * 512 * 4);
    float*          bufC  = (float*)alloc((size_t)NN_ * 512 * 4);
    // as_..cdn contiguous: first memset covers all six; re-zero covers first 3
    float*          as_   = (float*)alloc(NN_ * 4);
    float*          ad_   = (float*)alloc(NN_ * 4);
    float*          denom = (float*)alloc(NN_ * 4);
    int*            deg   = (int*)alloc(NN_ * 4);
    int*            cursor= (int*)alloc(NN_ * 4);
    float*          cdn   = (float*)alloc(NN_ * 4);    // per-chunk attn denoms
    int*            rowst = (int*)alloc((NN_ + 1) * 4);
    int*            csrs  = (int*)alloc((size_t)NE_ * 4);   // src per CSR slot
    int*            pos   = (int*)alloc((size_t)NE_ * 4);   // edge -> CSR slot
    float*          evs   = (float*)alloc((size_t)NE_ * 4); // exp in CSR order
    unsigned short* xbA   = (unsigned short*)alloc((size_t)NA_ * 256 * 2);
    unsigned short* xbB   = (unsigned short*)alloc((size_t)NB_ * 256 * 2);
    unsigned short* WbinA = (unsigned short*)alloc((size_t)512 * 256 * 2);
    unsigned short* WbinB = (unsigned short*)alloc((size_t)512 * 256 * 2);
    unsigned short* Wbin2A= (unsigned short*)alloc((size_t)512 * 256 * 2);
    unsigned short* Wbin2B= (unsigned short*)alloc((size_t)512 * 256 * 2);
    unsigned short* Wbqkv = (unsigned short*)alloc((size_t)1536 * 512 * 2);
    unsigned short* Wbo   = (unsigned short*)alloc((size_t)512 * 512 * 2);
    unsigned short* Wg1b  = (unsigned short*)alloc((size_t)512 * 512 * 2);
    unsigned short* Wg2b  = (unsigned short*)alloc((size_t)512 * 512 * 2);
    unsigned short* qb    = (unsigned short*)alloc((size_t)NN_ * 512 * 2);
    unsigned short* kb    = (unsigned short*)alloc((size_t)NN_ * 512 * 2);
    unsigned short* vT    = (unsigned short*)alloc((size_t)512 * NN_ * 2);
    unsigned short* ab    = (unsigned short*)alloc((size_t)NN_ * 512 * 2);

    // overlays
    unsigned short* hb = vT;                              // bf16 h (local branch)
    unsigned short* gb = (unsigned short*)bufC;           // g bf16 (global, pre-loop)
    unsigned short* vb = gb + (size_t)NN_ * 512;          // v bf16 (global, pre-loop)
    unsigned short* Sb = (unsigned short*)bufA;           // scores: bufA+bufB = 32MB
    unsigned short* pv = (unsigned short*)bufC;           // PV bf16 partials (16MB)

    const int R = 2048, SEGS = 8, KSEG = 8192 / SEGS;
    const int EG = (NE_ + 255) / 256;
    const float scale2 = 0.044194173824159216f * 1.4426950408889634f; // /sqrt(512)*log2e

    // -------- all weight/input casts in ONE launch --------------------------
    CvtJobs jobs;
    jobs.j[0] = { x_A,    xbA,    nullptr, NA_ * 256 / 4 };
    jobs.j[1] = { x_B,    xbB,    nullptr, NB_ * 256 / 4 };
    jobs.j[2] = { W_inA,  WbinA,  nullptr, 512 * 256 / 4 };
    jobs.j[3] = { W_inB,  WbinB,  nullptr, 512 * 256 / 4 };
    jobs.j[4] = { W_in2A, Wbin2A, nullptr, 512 * 256 / 4 };
    jobs.j[5] = { W_in2B, Wbin2B, nullptr, 512 * 256 / 4 };
    jobs.j[6] = { Wqkv,   Wbqkv,  nullptr, 1536 * 512 / 4 };
    jobs.j[7] = { Wo,     Wbo,    nullptr, 512 * 512 / 4 };
    jobs.j[8] = { Wg1,    Wg1b,   nullptr, 512 * 512 / 4 };
    jobs.j[9] = { Wg2,    Wg2b,   nullptr, 512 * 512 / 4 };
    cvt_all_k<<<dim3(NA_ * 256 / 4 / 256, 10), 256, 0, stream>>>(jobs);

    // zero as_, ad_, denom, deg, cursor, cdn in one shot
    hipMemsetAsync(as_, 0, (size_t)NN_ * 4 * 6, stream);

    // -------- CSR build -----------------------------------------------------
    count_deg_k<<<EG, 256, 0, stream>>>(eAB, eBA, deg);
    scan_k<<<1, 256, 0, stream>>>(deg, rowst);
    fill_csr_k<<<EG, 256, 0, stream>>>(eAB, eBA, rowst, cursor, csrs, pos);

    // -------- local branch --------------------------------------------------
    mgemm_in_k<true><<<dim3(4, 64), 256, 0, stream>>>(
        xbA, xbB, WbinA, WbinB, b_inA, b_inB, qb, kb);
    mgemm3_k<<<dim3(4, 64), 256, 0, stream>>>(qb, kb, Wg1b,
                                              hb, a_src1, a_dst1, as_, ad_,
                                              512, 512, 512);
    edge_fused_k<<<EG, 256, 0, stream>>>(eAB, eBA, as_, ad_, pos, evs, denom);
    gat_agg_k<true><<<NN_/4, 256, 0, stream>>>(rowst, csrs, evs, denom,
                                               hb, bg1, nullptr, 0, qb, kb);
    hipMemsetAsync(as_, 0, NN_ * 12, stream);           // as_, ad_, denom
    mgemm3_k<<<dim3(4, 64), 256, 0, stream>>>(qb, kb, Wg2b,
                                              hb, a_src2, a_dst2, as_, ad_,
                                              512, 512, 512);
    edge_fused_k<<<EG, 256, 0, stream>>>(eAB, eBA, as_, ad_, pos, evs, denom);
    // layer-2 aggregation writes the local half of d_out directly (ldo=1024)
    gat_agg_k<false><<<NN_/4, 256, 0, stream>>>(rowst, csrs, evs, denom,
                                                hb, bg2, out, 1024, nullptr, nullptr);

    // -------- global branch -------------------------------------------------
    mgemm_in_k<false><<<dim3(4, 64), 256, 0, stream>>>(
        xbA, xbB, Wbin2A, Wbin2B, b_in2A, b_in2B, gb, nullptr);
    mgemm_qkv_k<<<dim3(12, 64), 256, 0, stream>>>(gb, Wbqkv, bqkv, scale2, qb, kb, vb);
    trT_k<<<dim3(8, 128), 256, 0, stream>>>(vb, vT);
    for (int c0 = 0; c0 < 8192; c0 += R) {
        float* dn = cdn + c0;   // this chunk's 2048 denominators (pre-zeroed)
        mgemm_qk_k<<<dim3(64, 16), 256, 0, stream>>>(
            qb + (size_t)c0 * 512, kb, Sb, dn);
        mgemm_pv_k<<<dim3(4, R/128, SEGS), 256, 0, stream>>>(
            Sb, vT, pv, KSEG, (size_t)R * 512);
        radd_k<<<(R*512/8 + 255)/256, 256, 0, stream>>>(
            pv, ab + (size_t)c0 * 512, dn, R*512/8, SEGS, (size_t)R*512/8);
    }
    // Wo GEMM writes the global half of d_out directly (ldc=1024, col offset 512)
    mgemm_k<128,128,true,float><<<dim3(4, 64), 256, 0, stream>>>(
        ab, Wbo, bo, out + 512, 512, 512, 512, 1024);
}

// Round 20
// 528.818 us; speedup vs baseline: 1.0755x; 1.0755x over previous
//
#include <hip/hip_runtime.h>
#include <hip/hip_bf16.h>

#define NA_ 4096
#define NB_ 4096
#define NN_ 8192            // total nodes
#define EE_ 131072          // edges per direction
#define NE_ (2*EE_ + NN_)   // homogeneous edges incl. self loops = 270336
#define HH_ 512
#define NEG_SLOPE_ 0.2f

typedef __attribute__((ext_vector_type(4))) float f32x4;
typedef __attribute__((ext_vector_type(8))) short s16x8;

__device__ inline unsigned short f2bf(float v) {
    __hip_bfloat16 h = __float2bfloat16(v);
    return __builtin_bit_cast(unsigned short, h);
}
__device__ inline float bf2f(unsigned short u) {
    return __uint_as_float(((unsigned)u) << 16);
}

#define GLOAD16(gsrc, ldst)                                                    \
    __builtin_amdgcn_global_load_lds(                                          \
        (const __attribute__((address_space(1))) unsigned int*)(gsrc),         \
        (__attribute__((address_space(3))) unsigned int*)(ldst), 16, 0, 0)

// ---------------- homogeneous edge id -> (src, dst) ------------------------
__device__ inline void edge_sd(int i, const int* __restrict__ eAB,
                               const int* __restrict__ eBA, int& s, int& d) {
    if (i < EE_)            { s = eAB[i];            d = eAB[EE_ + i] + NA_; }
    else if (i < 2 * EE_)   { int j = i - EE_; s = eBA[j] + NA_; d = eBA[EE_ + j]; }
    else                    { s = i - 2 * EE_;       d = s; }
}

// ---------------- batched f32 -> bf16 (optionally split hi/lo) casts --------
struct CvtJob { const float* s; unsigned short* hi; unsigned short* lo; int n4; };
struct CvtJobs { CvtJob j[10]; };

__global__ __launch_bounds__(256) void cvt_all_k(CvtJobs jobs) {
    const CvtJob jb = jobs.j[blockIdx.y];
    int i = blockIdx.x * 256 + threadIdx.x;
    if (i >= jb.n4) return;
    float4 v = ((const float4*)jb.s)[i];
    ushort4 h;
    h.x = f2bf(v.x); h.y = f2bf(v.y); h.z = f2bf(v.z); h.w = f2bf(v.w);
    ((ushort4*)jb.hi)[i] = h;
    if (jb.lo) {
        ushort4 l;
        l.x = f2bf(v.x - bf2f(h.x));
        l.y = f2bf(v.y - bf2f(h.y));
        l.z = f2bf(v.z - bf2f(h.z));
        l.w = f2bf(v.w - bf2f(h.w));
        ((ushort4*)jb.lo)[i] = l;
    }
}

// ---------------- MFMA bf16 GEMM: C[M,N] = A @ B^T (+bias) -----------------
template<int BM, int BN, bool BIAS, typename OutT>
__global__ __launch_bounds__(256) void mgemm_k(
    const unsigned short* __restrict__ A, const unsigned short* __restrict__ B,
    const float* __restrict__ bias, OutT* __restrict__ C,
    int K, int lda, int ldb, int ldc)
{
    constexpr int BK = 32;
    constexpr int WM = BM / 2, WN = BN / 2;
    constexpr int AM = WM / 16, AN = WN / 16;
    constexpr int AISS = BM * 4 / 256, BISS = BN * 4 / 256;
    __shared__ unsigned short sA[BM * BK];
    __shared__ unsigned short sB[BN * BK];
    const int t = threadIdx.x, lane = t & 63, w = t >> 6;
    const int wr = w >> 1, wc = w & 1;
    const int fr = lane & 15, fq = lane >> 4;
    const int bm = blockIdx.y * BM, bn = blockIdx.x * BN;

    f32x4 acc[AM][AN];
    #pragma unroll
    for (int m = 0; m < AM; m++)
        #pragma unroll
        for (int n = 0; n < AN; n++)
            #pragma unroll
            for (int r = 0; r < 4; r++) acc[m][n][r] = 0.f;

    for (int k0 = 0; k0 < K; k0 += BK) {
        __syncthreads();
        #pragma unroll
        for (int i = 0; i < AISS; i++) {
            int slot = i * 256 + t;
            GLOAD16(A + (size_t)(bm + (slot >> 2)) * lda + k0 + (slot & 3) * 8,
                    sA + (i * 256 + w * 64) * 8);
        }
        #pragma unroll
        for (int i = 0; i < BISS; i++) {
            int slot = i * 256 + t;
            GLOAD16(B + (size_t)(bn + (slot >> 2)) * ldb + k0 + (slot & 3) * 8,
                    sB + (i * 256 + w * 64) * 8);
        }
        __syncthreads();
        s16x8 a[AM], b[AN];
        #pragma unroll
        for (int m = 0; m < AM; m++)
            a[m] = *(const s16x8*)&sA[(wr * WM + m * 16 + fr) * BK + fq * 8];
        #pragma unroll
        for (int n = 0; n < AN; n++)
            b[n] = *(const s16x8*)&sB[(wc * WN + n * 16 + fr) * BK + fq * 8];
        #pragma unroll
        for (int m = 0; m < AM; m++)
            #pragma unroll
            for (int n = 0; n < AN; n++)
                acc[m][n] = __builtin_amdgcn_mfma_f32_16x16x32_bf16(a[m], b[n], acc[m][n], 0, 0, 0);
    }

    #pragma unroll
    for (int m = 0; m < AM; m++) {
        const int row = bm + wr * WM + m * 16 + fq * 4;
        #pragma unroll
        for (int n = 0; n < AN; n++) {
            const int col = bn + wc * WN + n * 16 + fr;
            const float bv = BIAS ? bias[col] : 0.f;
            #pragma unroll
            for (int r = 0; r < 4; r++) {
                float v = acc[m][n][r] + bv;
                if constexpr (sizeof(OutT) == 2)
                    C[(size_t)(row + r) * ldc + col] = (OutT)f2bf(v);
                else
                    C[(size_t)(row + r) * ldc + col] = v;
            }
        }
    }
}

// ---------------- QK^T: 256x128 tile, 8 waves (4Mx2N), dbuf BK=32 -----------
// 2 blocks/CU co-resident (grid 512): barrier drain of one block overlaps the
// other block's compute (m114 mechanism). q pre-scaled by scale*log2e.
__global__ __launch_bounds__(512, 4) void mgemm_qk_k(
    const unsigned short* __restrict__ A, const unsigned short* __restrict__ B,
    unsigned short* __restrict__ C, float* __restrict__ denom)
{
    constexpr int BK = 32;
    __shared__ unsigned short smem[24576];    // 48KB: 2 bufs x (A 16KB | B 8KB)
    const int t = threadIdx.x, lane = t & 63, w = t >> 6;   // 8 waves
    const int wr = w >> 1, wc = w & 1;        // 4 (M) x 2 (N)
    const int fr = lane & 15, fq = lane >> 4;
    const int bm = blockIdx.y * 256, bn = blockIdx.x * 128;

    f32x4 acc[4][4];
    #pragma unroll
    for (int m = 0; m < 4; m++)
        #pragma unroll
        for (int n = 0; n < 4; n++)
            #pragma unroll
            for (int r = 0; r < 4; r++) acc[m][n][r] = 0.f;

    auto stage = [&](int buf, int k0) {       // 3 gloads per thread
        unsigned short* dA = smem + buf * 12288;
        unsigned short* dB = dA + 8192;
        #pragma unroll
        for (int i = 0; i < 2; i++) {
            int s = i * 512 + t;              // 1024 slots = 256 rows x 4 cc
            int row = s >> 2, cc = s & 3;
            int gc = k0 + ((cc ^ (row & 3)) << 3);
            GLOAD16(A + (size_t)(bm + row) * 512 + gc, dA + (i * 512 + w * 64) * 8);
        }
        {
            int row = t >> 2, cc = t & 3;     // 512 slots = 128 rows x 4 cc
            int gc = k0 + ((cc ^ (row & 3)) << 3);
            GLOAD16(B + (size_t)(bn + row) * 512 + gc, dB + (size_t)t * 8);
        }
    };

    stage(0, 0);
    asm volatile("s_waitcnt vmcnt(0)" ::: "memory");
    __builtin_amdgcn_s_barrier();
    int cur = 0;
    for (int k0 = 0; k0 < 512; k0 += BK) {
        if (k0 + BK < 512) stage(cur ^ 1, k0 + BK);
        const unsigned short* rA = smem + cur * 12288;
        const unsigned short* rB = rA + 8192;
        s16x8 a[4], b[4];
        #pragma unroll
        for (int m = 0; m < 4; m++) {
            int row = wr * 64 + m * 16 + fr;
            a[m] = *(const s16x8*)&rA[row * BK + ((fq ^ (row & 3)) << 3)];
        }
        #pragma unroll
        for (int n = 0; n < 4; n++) {
            int row = wc * 64 + n * 16 + fr;
            b[n] = *(const s16x8*)&rB[row * BK + ((fq ^ (row & 3)) << 3)];
        }
        __builtin_amdgcn_s_setprio(1);
        #pragma unroll
        for (int m = 0; m < 4; m++)
            #pragma unroll
            for (int n = 0; n < 4; n++)
                acc[m][n] = __builtin_amdgcn_mfma_f32_16x16x32_bf16(a[m], b[n], acc[m][n], 0, 0, 0);
        __builtin_amdgcn_s_setprio(0);
        asm volatile("s_waitcnt vmcnt(0)" ::: "memory");
        __builtin_amdgcn_s_barrier();
        cur ^= 1;
    }

    // epilogue: exp2 + row-sum (atomic) + direct stores (32B runs)
    #pragma unroll
    for (int m = 0; m < 4; m++) {
        #pragma unroll
        for (int r = 0; r < 4; r++) {
            const int row = bm + wr * 64 + m * 16 + fq * 4 + r;   // chunk-local
            float rsum = 0.f;
            #pragma unroll
            for (int n = 0; n < 4; n++) {
                float p = exp2f(acc[m][n][r]);
                rsum += p;
                C[(size_t)row * 8192 + bn + wc * 64 + n * 16 + fr] = f2bf(p);
            }
            rsum += __shfl_xor(rsum, 1);
            rsum += __shfl_xor(rsum, 2);
            rsum += __shfl_xor(rsum, 4);
            rsum += __shfl_xor(rsum, 8);
            if (fr == 0) atomicAdd(&denom[row], rsum);
        }
    }
}

// ---------------- merged per-type input linear (A rows 0..4095, B rows 4096+)
template<bool SPLIT>
__global__ __launch_bounds__(256) void mgemm_in_k(
    const unsigned short* __restrict__ xA, const unsigned short* __restrict__ xB,
    const unsigned short* __restrict__ WA, const unsigned short* __restrict__ WB,
    const float* __restrict__ biasA, const float* __restrict__ biasB,
    unsigned short* __restrict__ o1, unsigned short* __restrict__ o2)
{
    constexpr int BK = 32;
    __shared__ unsigned short sA[128 * BK];
    __shared__ unsigned short sB[128 * BK];
    const int t = threadIdx.x, lane = t & 63, w = t >> 6;
    const int wr = w >> 1, wc = w & 1;
    const int fr = lane & 15, fq = lane >> 4;
    const int bm = blockIdx.y * 128, bn = blockIdx.x * 128;
    const bool isB = bm >= NA_;
    const unsigned short* A = isB ? xB : xA;
    const unsigned short* W = isB ? WB : WA;
    const float* bias = isB ? biasB : biasA;
    const int bml = bm - (isB ? NA_ : 0);

    f32x4 acc[4][4];
    #pragma unroll
    for (int m = 0; m < 4; m++)
        #pragma unroll
        for (int n = 0; n < 4; n++)
            #pragma unroll
            for (int r = 0; r < 4; r++) acc[m][n][r] = 0.f;

    for (int k0 = 0; k0 < 256; k0 += BK) {
        __syncthreads();
        #pragma unroll
        for (int i = 0; i < 2; i++) {
            int slot = i * 256 + t;
            GLOAD16(A + (size_t)(bml + (slot >> 2)) * 256 + k0 + (slot & 3) * 8,
                    sA + (i * 256 + w * 64) * 8);
            GLOAD16(W + (size_t)(bn + (slot >> 2)) * 256 + k0 + (slot & 3) * 8,
                    sB + (i * 256 + w * 64) * 8);
        }
        __syncthreads();
        s16x8 a[4], b[4];
        #pragma unroll
        for (int m = 0; m < 4; m++)
            a[m] = *(const s16x8*)&sA[(wr * 64 + m * 16 + fr) * BK + fq * 8];
        #pragma unroll
        for (int n = 0; n < 4; n++)
            b[n] = *(const s16x8*)&sB[(wc * 64 + n * 16 + fr) * BK + fq * 8];
        #pragma unroll
        for (int m = 0; m < 4; m++)
            #pragma unroll
            for (int n = 0; n < 4; n++)
                acc[m][n] = __builtin_amdgcn_mfma_f32_16x16x32_bf16(a[m], b[n], acc[m][n], 0, 0, 0);
    }

    #pragma unroll
    for (int m = 0; m < 4; m++) {
        const int row = bm + wr * 64 + m * 16 + fq * 4;
        #pragma unroll
        for (int n = 0; n < 4; n++) {
            const int col = bn + wc * 64 + n * 16 + fr;
            const float bv = bias[col];
            #pragma unroll
            for (int r = 0; r < 4; r++) {
                float v = acc[m][n][r] + bv;
                unsigned short hi = f2bf(v);
                o1[(size_t)(row + r) * 512 + col] = hi;
                if (SPLIT)
                    o2[(size_t)(row + r) * 512 + col] = f2bf(v - bf2f(hi));
            }
        }
    }
}

// ---------------- split-A MFMA GEMM (2 MFMA), dbuf pipeline + fused dots ----
__global__ __launch_bounds__(256) void mgemm3_k(
    const unsigned short* __restrict__ Ahi, const unsigned short* __restrict__ Alo,
    const unsigned short* __restrict__ Bhi,
    unsigned short* __restrict__ Cb, const float* __restrict__ a_src,
    const float* __restrict__ a_dst, float* __restrict__ as_,
    float* __restrict__ ad_, int K, int lda, int ldb)
{
    constexpr int BK = 32;
    __shared__ unsigned short smem[24576];    // 48KB: 2 bufs x (Ah|Al|Bh) x 8KB
    const int t = threadIdx.x, lane = t & 63, w = t >> 6;
    const int wr = w >> 1, wc = w & 1;
    const int fr = lane & 15, fq = lane >> 4;
    const int bm = blockIdx.y * 128, bn = blockIdx.x * 128;

    f32x4 acc[4][4];
    #pragma unroll
    for (int m = 0; m < 4; m++)
        #pragma unroll
        for (int n = 0; n < 4; n++)
            #pragma unroll
            for (int r = 0; r < 4; r++) acc[m][n][r] = 0.f;

    auto stage = [&](int buf, int k0) {
        unsigned short* dAh = smem + buf * 12288;
        unsigned short* dAl = dAh + 4096;
        unsigned short* dBh = dAh + 8192;
        #pragma unroll
        for (int i = 0; i < 2; i++) {
            int s = i * 256 + t;              // 512 slots = 128 rows x 4 cc
            int row = s >> 2, cc = s & 3;
            int gco = (cc ^ (row & 3)) << 3;
            size_t ga = (size_t)(bm + row) * lda + k0 + gco;
            size_t gb = (size_t)(bn + row) * ldb + k0 + gco;
            unsigned loff = (unsigned)(i * 256 + w * 64) * 8;
            GLOAD16(Ahi + ga, dAh + loff);
            GLOAD16(Alo + ga, dAl + loff);
            GLOAD16(Bhi + gb, dBh + loff);
        }
    };

    stage(0, 0);
    asm volatile("s_waitcnt vmcnt(0)" ::: "memory");
    __builtin_amdgcn_s_barrier();
    int cur = 0;
    for (int k0 = 0; k0 < K; k0 += BK) {
        if (k0 + BK < K) stage(cur ^ 1, k0 + BK);
        const unsigned short* rAh = smem + cur * 12288;
        const unsigned short* rAl = rAh + 4096;
        const unsigned short* rBh = rAh + 8192;
        s16x8 ah[4], al[4], bh[4];
        #pragma unroll
        for (int m = 0; m < 4; m++) {
            int row = wr * 64 + m * 16 + fr;
            int o = row * BK + ((fq ^ (row & 3)) << 3);
            ah[m] = *(const s16x8*)&rAh[o];
            al[m] = *(const s16x8*)&rAl[o];
        }
        #pragma unroll
        for (int n = 0; n < 4; n++) {
            int row = wc * 64 + n * 16 + fr;
            bh[n] = *(const s16x8*)&rBh[row * BK + ((fq ^ (row & 3)) << 3)];
        }
        __builtin_amdgcn_s_setprio(1);
        #pragma unroll
        for (int m = 0; m < 4; m++)
            #pragma unroll
            for (int n = 0; n < 4; n++) {
                acc[m][n] = __builtin_amdgcn_mfma_f32_16x16x32_bf16(ah[m], bh[n], acc[m][n], 0, 0, 0);
                acc[m][n] = __builtin_amdgcn_mfma_f32_16x16x32_bf16(al[m], bh[n], acc[m][n], 0, 0, 0);
            }
        __builtin_amdgcn_s_setprio(0);
        asm volatile("s_waitcnt vmcnt(0)" ::: "memory");
        __builtin_amdgcn_s_barrier();
        cur ^= 1;
    }

    float asv[4], adv[4];
    #pragma unroll
    for (int n = 0; n < 4; n++) {
        const int col = bn + wc * 64 + n * 16 + fr;
        asv[n] = a_src[col];
        adv[n] = a_dst[col];
    }

    #pragma unroll
    for (int m = 0; m < 4; m++) {
        const int row = bm + wr * 64 + m * 16 + fq * 4;
        #pragma unroll
        for (int r = 0; r < 4; r++) {
            float s1 = 0.f, s2 = 0.f;
            #pragma unroll
            for (int n = 0; n < 4; n++) {
                const int col = bn + wc * 64 + n * 16 + fr;
                float v = acc[m][n][r];
                Cb[(size_t)(row + r) * 512 + col] = f2bf(v);
                s1 = fmaf(v, asv[n], s1);
                s2 = fmaf(v, adv[n], s2);
            }
            s1 += __shfl_xor(s1, 1); s2 += __shfl_xor(s2, 1);
            s1 += __shfl_xor(s1, 2); s2 += __shfl_xor(s2, 2);
            s1 += __shfl_xor(s1, 4); s2 += __shfl_xor(s2, 4);
            s1 += __shfl_xor(s1, 8); s2 += __shfl_xor(s2, 8);
            if (fr == 0) {
                atomicAdd(&as_[row + r], s1);
                atomicAdd(&ad_[row + r], s2);
            }
        }
    }
}

// ---------------- PV split-K: dbuf BK=32 pipeline, XCD swizzle --------------
__global__ __launch_bounds__(256) void mgemm_pv_k(
    const unsigned short* __restrict__ A, const unsigned short* __restrict__ B,
    unsigned short* __restrict__ C, int kseg, size_t segstride)
{
    constexpr int BK = 32;
    __shared__ unsigned short smem[16384];    // 32KB: 2 bufs x (A 8KB | B 8KB)
    const int t = threadIdx.x, lane = t & 63, w = t >> 6;
    const int wr = w >> 1, wc = w & 1;
    const int fr = lane & 15, fq = lane >> 4;
    const int L  = blockIdx.x + (blockIdx.y << 2) + (blockIdx.z << 6);
    const int xs = L >> 7;
    const int ys = (L & 127) & 15;
    const int zs = (L & 127) >> 4;
    const int bm = ys * 128, bn = xs * 128;
    const int kofs = zs * kseg;

    f32x4 acc[4][4];
    #pragma unroll
    for (int m = 0; m < 4; m++)
        #pragma unroll
        for (int n = 0; n < 4; n++)
            #pragma unroll
            for (int r = 0; r < 4; r++) acc[m][n][r] = 0.f;

    auto stage = [&](int buf, int k0) {
        unsigned short* dA = smem + buf * 8192;
        unsigned short* dB = dA + 4096;
        #pragma unroll
        for (int i = 0; i < 2; i++) {
            int s = i * 256 + t;              // 512 slots = 128 rows x 4 cc
            int row = s >> 2, cc = s & 3;
            int gc = kofs + k0 + ((cc ^ (row & 3)) << 3);
            GLOAD16(A + (size_t)(bm + row) * 8192 + gc, dA + (i * 256 + w * 64) * 8);
            GLOAD16(B + (size_t)(bn + row) * 8192 + gc, dB + (i * 256 + w * 64) * 8);
        }
    };

    stage(0, 0);
    asm volatile("s_waitcnt vmcnt(0)" ::: "memory");
    __builtin_amdgcn_s_barrier();
    int cur = 0;
    for (int k0 = 0; k0 < kseg; k0 += BK) {
        if (k0 + BK < kseg) stage(cur ^ 1, k0 + BK);
        const unsigned short* rA = smem + cur * 8192;
        const unsigned short* rB = rA + 4096;
        s16x8 a[4], b[4];
        #pragma unroll
        for (int m = 0; m < 4; m++) {
            int row = wr * 64 + m * 16 + fr;
            a[m] = *(const s16x8*)&rA[row * BK + ((fq ^ (row & 3)) << 3)];
        }
        #pragma unroll
        for (int n = 0; n < 4; n++) {
            int row = wc * 64 + n * 16 + fr;
            b[n] = *(const s16x8*)&rB[row * BK + ((fq ^ (row & 3)) << 3)];
        }
        __builtin_amdgcn_s_setprio(1);
        #pragma unroll
        for (int m = 0; m < 4; m++)
            #pragma unroll
            for (int n = 0; n < 4; n++)
                acc[m][n] = __builtin_amdgcn_mfma_f32_16x16x32_bf16(a[m], b[n], acc[m][n], 0, 0, 0);
        __builtin_amdgcn_s_setprio(0);
        asm volatile("s_waitcnt vmcnt(0)" ::: "memory");
        __builtin_amdgcn_s_barrier();
        cur ^= 1;
    }

    unsigned short* Cz = C + (size_t)zs * segstride;
    #pragma unroll
    for (int m = 0; m < 4; m++) {
        const int row = bm + wr * 64 + m * 16 + fq * 4;
        #pragma unroll
        for (int n = 0; n < 4; n++) {
            const int col = bn + wc * 64 + n * 16 + fr;
            #pragma unroll
            for (int r = 0; r < 4; r++)
                Cz[(size_t)(row + r) * 512 + col] = f2bf(acc[m][n][r]);
        }
    }
}

// ---------------- reduce bf16 split-K partials, divide by denom -> bf16 ----
__global__ __launch_bounds__(256) void radd_k(const unsigned short* __restrict__ src,
                                              unsigned short* __restrict__ dst,
                                              const float* __restrict__ dn,
                                              int n8, int segs, size_t stride8) {
    int i = blockIdx.x * 256 + threadIdx.x;
    if (i >= n8) return;
    float acc[8] = {0,0,0,0,0,0,0,0};
    for (int s = 0; s < segs; s++) {
        s16x8 v = ((const s16x8*)src)[i + s * stride8];
        #pragma unroll
        for (int j = 0; j < 8; j++) acc[j] += bf2f((unsigned short)v[j]);
    }
    const float rd = 1.0f / dn[i >> 6];    // 64 groups of 8 per 512-col row
    s16x8 o;
    #pragma unroll
    for (int j = 0; j < 8; j++) o[j] = (short)f2bf(acc[j] * rd);
    ((s16x8*)dst)[i] = o;
}

// ---------------- qkv MFMA GEMM with split epilogue (scale folded into q) ---
__global__ __launch_bounds__(256) void mgemm_qkv_k(
    const unsigned short* __restrict__ A, const unsigned short* __restrict__ B,
    const float* __restrict__ bias, float scale,
    unsigned short* __restrict__ qb, unsigned short* __restrict__ kb,
    unsigned short* __restrict__ vb)
{
    constexpr int BM = 128, BN = 128, BK = 32;
    __shared__ unsigned short sA[BM * BK];
    __shared__ unsigned short sB[BN * BK];
    const int t = threadIdx.x, lane = t & 63, w = t >> 6;
    const int wr = w >> 1, wc = w & 1;
    const int fr = lane & 15, fq = lane >> 4;
    const int bm = blockIdx.y * BM, bn = blockIdx.x * BN;

    f32x4 acc[4][4];
    #pragma unroll
    for (int m = 0; m < 4; m++)
        #pragma unroll
        for (int n = 0; n < 4; n++)
            #pragma unroll
            for (int r = 0; r < 4; r++) acc[m][n][r] = 0.f;

    for (int k0 = 0; k0 < 512; k0 += BK) {
        __syncthreads();
        #pragma unroll
        for (int i = 0; i < 2; i++) {
            int slot = i * 256 + t;
            GLOAD16(A + (size_t)(bm + (slot >> 2)) * 512 + k0 + (slot & 3) * 8,
                    sA + (i * 256 + w * 64) * 8);
            GLOAD16(B + (size_t)(bn + (slot >> 2)) * 512 + k0 + (slot & 3) * 8,
                    sB + (i * 256 + w * 64) * 8);
        }
        __syncthreads();
        s16x8 a[4], b[4];
        #pragma unroll
        for (int m = 0; m < 4; m++)
            a[m] = *(const s16x8*)&sA[(wr * 64 + m * 16 + fr) * BK + fq * 8];
        #pragma unroll
        for (int n = 0; n < 4; n++)
            b[n] = *(const s16x8*)&sB[(wc * 64 + n * 16 + fr) * BK + fq * 8];
        #pragma unroll
        for (int m = 0; m < 4; m++)
            #pragma unroll
            for (int n = 0; n < 4; n++)
                acc[m][n] = __builtin_amdgcn_mfma_f32_16x16x32_bf16(a[m], b[n], acc[m][n], 0, 0, 0);
    }

    #pragma unroll
    for (int m = 0; m < 4; m++) {
        const int row = bm + wr * 64 + m * 16 + fq * 4;
        #pragma unroll
        for (int n = 0; n < 4; n++) {
            const int col = bn + wc * 64 + n * 16 + fr;
            const float bv = bias[col];
            #pragma unroll
            for (int r = 0; r < 4; r++) {
                float v = acc[m][n][r] + bv;
                if (col < 512)
                    qb[(size_t)(row + r) * 512 + col] = f2bf(v * scale);
                else if (col < 1024)
                    kb[(size_t)(row + r) * 512 + (col - 512)] = f2bf(v);
                else
                    vb[(size_t)(row + r) * 512 + (col - 1024)] = f2bf(v);
            }
        }
    }
}

// ---------------- bf16 transpose: vb[8192][512] -> vT[512][8192] ------------
__global__ __launch_bounds__(256) void trT_k(const unsigned short* __restrict__ vb,
                                             unsigned short* __restrict__ vT) {
    __shared__ unsigned short s[64][65];
    const int t = threadIdx.x;
    const int rowo = blockIdx.y * 64;
    const int colo = blockIdx.x * 64;
    {
        int r = t >> 2, cg = (t & 3) * 16;
        const s16x8* src = (const s16x8*)(vb + (size_t)(rowo + r) * 512 + colo + cg);
        s16x8 u0 = src[0], u1 = src[1];
        #pragma unroll
        for (int j = 0; j < 8; j++) {
            s[r][cg + j]     = (unsigned short)u0[j];
            s[r][cg + 8 + j] = (unsigned short)u1[j];
        }
    }
    __syncthreads();
    {
        int c = t >> 2, rg = (t & 3) * 16;
        s16x8 o0, o1;
        #pragma unroll
        for (int j = 0; j < 8; j++) {
            o0[j] = (short)s[rg + j][c];
            o1[j] = (short)s[rg + 8 + j][c];
        }
        s16x8* dst = (s16x8*)(vT + (size_t)(colo + c) * 8192 + rowo + rg);
        dst[0] = o0; dst[1] = o1;
    }
}

// ---------------- CSR build ------------------------------------------------
__global__ void count_deg_k(const int* eAB, const int* eBA, int* deg) {
    int i = blockIdx.x * 256 + threadIdx.x;
    if (i >= NE_) return;
    int s, d; edge_sd(i, eAB, eBA, s, d);
    atomicAdd(&deg[d], 1);
}

__global__ __launch_bounds__(256) void scan_k(const int* __restrict__ deg, int* rowstart) {
    __shared__ int part[256];
    int t = threadIdx.x;
    int base = t * 32;
    int loc[32]; int s = 0;
    #pragma unroll
    for (int j = 0; j < 32; j++) { loc[j] = s; s += deg[base + j]; }
    part[t] = s;
    __syncthreads();
    if (t == 0) {
        int a = 0;
        for (int i = 0; i < 256; i++) { int v = part[i]; part[i] = a; a += v; }
        rowstart[NN_] = a;
    }
    __syncthreads();
    int off = part[t];
    #pragma unroll
    for (int j = 0; j < 32; j++) rowstart[base + j] = off + loc[j];
}

__global__ void fill_csr_k(const int* eAB, const int* eBA,
                           const int* __restrict__ rowstart, int* cursor,
                           int* csr_src, int* pos) {
    int i = blockIdx.x * 256 + threadIdx.x;
    if (i >= NE_) return;
    int s, d; edge_sd(i, eAB, eBA, s, d);
    int p = atomicAdd(&cursor[d], 1);
    int slot = rowstart[d] + p;
    csr_src[slot] = s;
    pos[i] = slot;
}

// ---------------- fused GAT edge pass: e -> exp(e) scatter + denom ----------
__global__ void edge_fused_k(const int* eAB, const int* eBA,
                             const float* __restrict__ as_, const float* __restrict__ ad_,
                             const int* __restrict__ pos,
                             float* __restrict__ evs, float* __restrict__ denom) {
    int i = blockIdx.x * 256 + threadIdx.x;
    if (i >= NE_) return;
    int s, d; edge_sd(i, eAB, eBA, s, d);
    float e = as_[s] + ad_[d];
    e = (e >= 0.f) ? e : NEG_SLOPE_ * e;
    float ex = expf(e);
    evs[pos[i]] = ex;
    atomicAdd(&denom[d], ex);
}

// ---------------- GAT aggregation: streaming CSR, 4-edge unrolled -----------
template<bool SPLIT>
__global__ __launch_bounds__(256) void gat_agg_k(
    const int* __restrict__ rowstart, const int* __restrict__ csr_src,
    const float* __restrict__ evs, const float* __restrict__ denom,
    const unsigned short* __restrict__ hb, const float* __restrict__ bias,
    float* __restrict__ outF, int ldo,
    unsigned short* __restrict__ outHi, unsigned short* __restrict__ outLo)
{
    int wid  = (blockIdx.x * 256 + threadIdx.x) >> 6;
    int lane = threadIdx.x & 63;
    if (wid >= NN_) return;
    float acc[8] = {0.f,0.f,0.f,0.f,0.f,0.f,0.f,0.f};
    int beg = rowstart[wid], end = rowstart[wid + 1];
    float rden = 1.0f / denom[wid];
    int p = beg;
    for (; p + 3 < end; p += 4) {
        int s0 = csr_src[p],     s1 = csr_src[p + 1];
        int s2 = csr_src[p + 2], s3 = csr_src[p + 3];
        float al0 = evs[p] * rden,     al1 = evs[p + 1] * rden;
        float al2 = evs[p + 2] * rden, al3 = evs[p + 3] * rden;
        s16x8 h0 = *(const s16x8*)(hb + (size_t)s0 * HH_ + lane * 8);
        s16x8 h1 = *(const s16x8*)(hb + (size_t)s1 * HH_ + lane * 8);
        s16x8 h2 = *(const s16x8*)(hb + (size_t)s2 * HH_ + lane * 8);
        s16x8 h3 = *(const s16x8*)(hb + (size_t)s3 * HH_ + lane * 8);
        #pragma unroll
        for (int j = 0; j < 8; j++) {
            float x = fmaf(al0, bf2f((unsigned short)h0[j]),
                      fmaf(al1, bf2f((unsigned short)h1[j]), acc[j]));
            acc[j] = fmaf(al2, bf2f((unsigned short)h2[j]),
                     fmaf(al3, bf2f((unsigned short)h3[j]), x));
        }
    }
    for (; p < end; p++) {
        int s0 = csr_src[p];
        float al0 = evs[p] * rden;
        s16x8 h0 = *(const s16x8*)(hb + (size_t)s0 * HH_ + lane * 8);
        #pragma unroll
        for (int j = 0; j < 8; j++)
            acc[j] = fmaf(al0, bf2f((unsigned short)h0[j]), acc[j]);
    }
    #pragma unroll
    for (int j = 0; j < 8; j++) acc[j] += bias[lane * 8 + j];
    if (SPLIT) {
        s16x8 hi, lo;
        #pragma unroll
        for (int j = 0; j < 8; j++) {
            unsigned short h = f2bf(acc[j]);
            hi[j] = (short)h;
            lo[j] = (short)f2bf(acc[j] - bf2f(h));
        }
        *(s16x8*)(outHi + (size_t)wid * HH_ + lane * 8) = hi;
        *(s16x8*)(outLo + (size_t)wid * HH_ + lane * 8) = lo;
    } else {
        float* o = outF + (size_t)wid * ldo + lane * 8;
        *(float4*)(o)     = make_float4(acc[0], acc[1], acc[2], acc[3]);
        *(float4*)(o + 4) = make_float4(acc[4], acc[5], acc[6], acc[7]);
    }
}

// ===========================================================================
extern "C" void kernel_launch(void* const* d_in, const int* in_sizes, int n_in,
                              void* d_out, int out_size, void* d_ws, size_t ws_size,
                              hipStream_t stream)
{
    const float* x_A    = (const float*)d_in[0];
    const float* x_B    = (const float*)d_in[1];
    const int*   eAB    = (const int*)d_in[2];
    const int*   eBA    = (const int*)d_in[3];
    const float* W_inA  = (const float*)d_in[4];  const float* b_inA  = (const float*)d_in[5];
    const float* W_inB  = (const float*)d_in[6];  const float* b_inB  = (const float*)d_in[7];
    const float* W_in2A = (const float*)d_in[8];  const float* b_in2A = (const float*)d_in[9];
    const float* W_in2B = (const float*)d_in[10]; const float* b_in2B = (const float*)d_in[11];
    const float* Wg1    = (const float*)d_in[12]; const float* a_src1 = (const float*)d_in[13];
    const float* a_dst1 = (const float*)d_in[14]; const float* bg1    = (const float*)d_in[15];
    const float* Wg2    = (const float*)d_in[16]; const float* a_src2 = (const float*)d_in[17];
    const float* a_dst2 = (const float*)d_in[18]; const float* bg2    = (const float*)d_in[19];
    const float* Wqkv   = (const float*)d_in[20]; const float* bqkv   = (const float*)d_in[21];
    const float* Wo     = (const float*)d_in[22]; const float* bo     = (const float*)d_in[23];

    float* out = (float*)d_out;

    char* base = (char*)d_ws;
    size_t off = 0;
    auto alloc = [&](size_t nb) -> char* {
        char* p = base + off;
        off = (off + nb + 255) & ~(size_t)255;
        return p;
    };

    // bufA and bufB MUST be adjacent: Sb (32MB) spans both during attention.
    float*          bufA  = (float*)alloc((size_t)NN_ * 512 * 4);
    float*          bufB  = (float*)alloc((size_t)NN_ * 512 * 4);
    float*          bufC  = (float*)alloc((size_t)NN_ * 512 * 4);
    // as_..cdn contiguous: first memset covers all six; re-zero covers first 3
    float*          as_   = (float*)alloc(NN_ * 4);
    float*          ad_   = (float*)alloc(NN_ * 4);
    float*          denom = (float*)alloc(NN_ * 4);
    int*            deg   = (int*)alloc(NN_ * 4);
    int*            cursor= (int*)alloc(NN_ * 4);
    float*          cdn   = (float*)alloc(NN_ * 4);    // per-chunk attn denoms
    int*            rowst = (int*)alloc((NN_ + 1) * 4);
    int*            csrs  = (int*)alloc((size_t)NE_ * 4);   // src per CSR slot
    int*            pos   = (int*)alloc((size_t)NE_ * 4);   // edge -> CSR slot
    float*          evs   = (float*)alloc((size_t)NE_ * 4); // exp in CSR order
    unsigned short* xbA   = (unsigned short*)alloc((size_t)NA_ * 256 * 2);
    unsigned short* xbB   = (unsigned short*)alloc((size_t)NB_ * 256 * 2);
    unsigned short* WbinA = (unsigned short*)alloc((size_t)512 * 256 * 2);
    unsigned short* WbinB = (unsigned short*)alloc((size_t)512 * 256 * 2);
    unsigned short* Wbin2A= (unsigned short*)alloc((size_t)512 * 256 * 2);
    unsigned short* Wbin2B= (unsigned short*)alloc((size_t)512 * 256 * 2);
    unsigned short* Wbqkv = (unsigned short*)alloc((size_t)1536 * 512 * 2);
    unsigned short* Wbo   = (unsigned short*)alloc((size_t)512 * 512 * 2);
    unsigned short* Wg1b  = (unsigned short*)alloc((size_t)512 * 512 * 2);
    unsigned short* Wg2b  = (unsigned short*)alloc((size_t)512 * 512 * 2);
    unsigned short* qb    = (unsigned short*)alloc((size_t)NN_ * 512 * 2);
    unsigned short* kb    = (unsigned short*)alloc((size_t)NN_ * 512 * 2);
    unsigned short* vT    = (unsigned short*)alloc((size_t)512 * NN_ * 2);
    unsigned short* ab    = (unsigned short*)alloc((size_t)NN_ * 512 * 2);

    // overlays
    unsigned short* hb = vT;                              // bf16 h (local branch)
    unsigned short* gb = (unsigned short*)bufC;           // g bf16 (global, pre-loop)
    unsigned short* vb = gb + (size_t)NN_ * 512;          // v bf16 (global, pre-loop)
    unsigned short* Sb = (unsigned short*)bufA;           // scores: bufA+bufB = 32MB
    unsigned short* pv = (unsigned short*)bufC;           // PV bf16 partials (16MB)

    const int R = 2048, SEGS = 8, KSEG = 8192 / SEGS;
    const int EG = (NE_ + 255) / 256;
    const float scale2 = 0.044194173824159216f * 1.4426950408889634f; // /sqrt(512)*log2e

    // -------- all weight/input casts in ONE launch --------------------------
    CvtJobs jobs;
    jobs.j[0] = { x_A,    xbA,    nullptr, NA_ * 256 / 4 };
    jobs.j[1] = { x_B,    xbB,    nullptr, NB_ * 256 / 4 };
    jobs.j[2] = { W_inA,  WbinA,  nullptr, 512 * 256 / 4 };
    jobs.j[3] = { W_inB,  WbinB,  nullptr, 512 * 256 / 4 };
    jobs.j[4] = { W_in2A, Wbin2A, nullptr, 512 * 256 / 4 };
    jobs.j[5] = { W_in2B, Wbin2B, nullptr, 512 * 256 / 4 };
    jobs.j[6] = { Wqkv,   Wbqkv,  nullptr, 1536 * 512 / 4 };
    jobs.j[7] = { Wo,     Wbo,    nullptr, 512 * 512 / 4 };
    jobs.j[8] = { Wg1,    Wg1b,   nullptr, 512 * 512 / 4 };
    jobs.j[9] = { Wg2,    Wg2b,   nullptr, 512 * 512 / 4 };
    cvt_all_k<<<dim3(NA_ * 256 / 4 / 256, 10), 256, 0, stream>>>(jobs);

    // zero as_, ad_, denom, deg, cursor, cdn in one shot
    hipMemsetAsync(as_, 0, (size_t)NN_ * 4 * 6, stream);

    // -------- CSR build -----------------------------------------------------
    count_deg_k<<<EG, 256, 0, stream>>>(eAB, eBA, deg);
    scan_k<<<1, 256, 0, stream>>>(deg, rowst);
    fill_csr_k<<<EG, 256, 0, stream>>>(eAB, eBA, rowst, cursor, csrs, pos);

    // -------- local branch --------------------------------------------------
    mgemm_in_k<true><<<dim3(4, 64), 256, 0, stream>>>(
        xbA, xbB, WbinA, WbinB, b_inA, b_inB, qb, kb);
    mgemm3_k<<<dim3(4, 64), 256, 0, stream>>>(qb, kb, Wg1b,
                                              hb, a_src1, a_dst1, as_, ad_,
                                              512, 512, 512);
    edge_fused_k<<<EG, 256, 0, stream>>>(eAB, eBA, as_, ad_, pos, evs, denom);
    gat_agg_k<true><<<NN_/4, 256, 0, stream>>>(rowst, csrs, evs, denom,
                                               hb, bg1, nullptr, 0, qb, kb);
    hipMemsetAsync(as_, 0, NN_ * 12, stream);           // as_, ad_, denom
    mgemm3_k<<<dim3(4, 64), 256, 0, stream>>>(qb, kb, Wg2b,
                                              hb, a_src2, a_dst2, as_, ad_,
                                              512, 512, 512);
    edge_fused_k<<<EG, 256, 0, stream>>>(eAB, eBA, as_, ad_, pos, evs, denom);
    // layer-2 aggregation writes the local half of d_out directly (ldo=1024)
    gat_agg_k<false><<<NN_/4, 256, 0, stream>>>(rowst, csrs, evs, denom,
                                                hb, bg2, out, 1024, nullptr, nullptr);

    // -------- global branch -------------------------------------------------
    mgemm_in_k<false><<<dim3(4, 64), 256, 0, stream>>>(
        xbA, xbB, Wbin2A, Wbin2B, b_in2A, b_in2B, gb, nullptr);
    mgemm_qkv_k<<<dim3(12, 64), 256, 0, stream>>>(gb, Wbqkv, bqkv, scale2, qb, kb, vb);
    trT_k<<<dim3(8, 128), 256, 0, stream>>>(vb, vT);
    for (int c0 = 0; c0 < 8192; c0 += R) {
        float* dn = cdn + c0;   // this chunk's 2048 denominators (pre-zeroed)
        mgemm_qk_k<<<dim3(64, 8), 512, 0, stream>>>(
            qb + (size_t)c0 * 512, kb, Sb, dn);
        mgemm_pv_k<<<dim3(4, R/128, SEGS), 256, 0, stream>>>(
            Sb, vT, pv, KSEG, (size_t)R * 512);
        radd_k<<<(R*512/8 + 255)/256, 256, 0, stream>>>(
            pv, ab + (size_t)c0 * 512, dn, R*512/8, SEGS, (size_t)R*512/8);
    }
    // Wo GEMM writes the global half of d_out directly (ldc=1024, col offset 512)
    mgemm_k<128,128,true,float><<<dim3(4, 64), 256, 0, stream>>>(
        ab, Wbo, bo, out + 512, 512, 512, 512, 1024);
}

// Round 21
// 525.643 us; speedup vs baseline: 1.0820x; 1.0060x over previous
//
#include <hip/hip_runtime.h>
#include <hip/hip_bf16.h>

#define NA_ 4096
#define NB_ 4096
#define NN_ 8192            // total nodes
#define EE_ 131072          // edges per direction
#define NE_ (2*EE_ + NN_)   // homogeneous edges incl. self loops = 270336
#define HH_ 512
#define NEG_SLOPE_ 0.2f

typedef __attribute__((ext_vector_type(4))) float f32x4;
typedef __attribute__((ext_vector_type(8))) short s16x8;

__device__ inline unsigned short f2bf(float v) {
    __hip_bfloat16 h = __float2bfloat16(v);
    return __builtin_bit_cast(unsigned short, h);
}
__device__ inline float bf2f(unsigned short u) {
    return __uint_as_float(((unsigned)u) << 16);
}

#define GLOAD16(gsrc, ldst)                                                    \
    __builtin_amdgcn_global_load_lds(                                          \
        (const __attribute__((address_space(1))) unsigned int*)(gsrc),         \
        (__attribute__((address_space(3))) unsigned int*)(ldst), 16, 0, 0)

// ---------------- homogeneous edge id -> (src, dst) ------------------------
__device__ inline void edge_sd(int i, const int* __restrict__ eAB,
                               const int* __restrict__ eBA, int& s, int& d) {
    if (i < EE_)            { s = eAB[i];            d = eAB[EE_ + i] + NA_; }
    else if (i < 2 * EE_)   { int j = i - EE_; s = eBA[j] + NA_; d = eBA[EE_ + j]; }
    else                    { s = i - 2 * EE_;       d = s; }
}

// ---------------- batched f32 -> bf16 (optionally split hi/lo) casts --------
struct CvtJob { const float* s; unsigned short* hi; unsigned short* lo; int n4; };
struct CvtJobs { CvtJob j[10]; };

__global__ __launch_bounds__(256) void cvt_all_k(CvtJobs jobs) {
    const CvtJob jb = jobs.j[blockIdx.y];
    int i = blockIdx.x * 256 + threadIdx.x;
    if (i >= jb.n4) return;
    float4 v = ((const float4*)jb.s)[i];
    ushort4 h;
    h.x = f2bf(v.x); h.y = f2bf(v.y); h.z = f2bf(v.z); h.w = f2bf(v.w);
    ((ushort4*)jb.hi)[i] = h;
    if (jb.lo) {
        ushort4 l;
        l.x = f2bf(v.x - bf2f(h.x));
        l.y = f2bf(v.y - bf2f(h.y));
        l.z = f2bf(v.z - bf2f(h.z));
        l.w = f2bf(v.w - bf2f(h.w));
        ((ushort4*)jb.lo)[i] = l;
    }
}

// ---------------- Wo GEMM: out_half = ab @ Wbo^T + bo (dbuf pipeline) -------
__global__ __launch_bounds__(256) void mgemm_wo_k(
    const unsigned short* __restrict__ A, const unsigned short* __restrict__ B,
    const float* __restrict__ bias, float* __restrict__ C, int ldc)
{
    constexpr int BK = 32;
    __shared__ unsigned short smem[16384];    // 32KB: 2 bufs x (A 8KB | B 8KB)
    const int t = threadIdx.x, lane = t & 63, w = t >> 6;
    const int wr = w >> 1, wc = w & 1;
    const int fr = lane & 15, fq = lane >> 4;
    const int bm = blockIdx.y * 128, bn = blockIdx.x * 128;

    f32x4 acc[4][4];
    #pragma unroll
    for (int m = 0; m < 4; m++)
        #pragma unroll
        for (int n = 0; n < 4; n++)
            #pragma unroll
            for (int r = 0; r < 4; r++) acc[m][n][r] = 0.f;

    auto stage = [&](int buf, int k0) {
        unsigned short* dA = smem + buf * 8192;
        unsigned short* dB = dA + 4096;
        #pragma unroll
        for (int i = 0; i < 2; i++) {
            int s = i * 256 + t;              // 512 slots = 128 rows x 4 cc
            int row = s >> 2, cc = s & 3;
            int gc = k0 + ((cc ^ (row & 3)) << 3);
            GLOAD16(A + (size_t)(bm + row) * 512 + gc, dA + (i * 256 + w * 64) * 8);
            GLOAD16(B + (size_t)(bn + row) * 512 + gc, dB + (i * 256 + w * 64) * 8);
        }
    };

    stage(0, 0);
    asm volatile("s_waitcnt vmcnt(0)" ::: "memory");
    __builtin_amdgcn_s_barrier();
    int cur = 0;
    for (int k0 = 0; k0 < 512; k0 += BK) {
        if (k0 + BK < 512) stage(cur ^ 1, k0 + BK);
        const unsigned short* rA = smem + cur * 8192;
        const unsigned short* rB = rA + 4096;
        s16x8 a[4], b[4];
        #pragma unroll
        for (int m = 0; m < 4; m++) {
            int row = wr * 64 + m * 16 + fr;
            a[m] = *(const s16x8*)&rA[row * BK + ((fq ^ (row & 3)) << 3)];
        }
        #pragma unroll
        for (int n = 0; n < 4; n++) {
            int row = wc * 64 + n * 16 + fr;
            b[n] = *(const s16x8*)&rB[row * BK + ((fq ^ (row & 3)) << 3)];
        }
        __builtin_amdgcn_s_setprio(1);
        #pragma unroll
        for (int m = 0; m < 4; m++)
            #pragma unroll
            for (int n = 0; n < 4; n++)
                acc[m][n] = __builtin_amdgcn_mfma_f32_16x16x32_bf16(a[m], b[n], acc[m][n], 0, 0, 0);
        __builtin_amdgcn_s_setprio(0);
        asm volatile("s_waitcnt vmcnt(0)" ::: "memory");
        __builtin_amdgcn_s_barrier();
        cur ^= 1;
    }

    #pragma unroll
    for (int m = 0; m < 4; m++) {
        const int row = bm + wr * 64 + m * 16 + fq * 4;
        #pragma unroll
        for (int n = 0; n < 4; n++) {
            const int col = bn + wc * 64 + n * 16 + fr;
            const float bv = bias[col];
            #pragma unroll
            for (int r = 0; r < 4; r++)
                C[(size_t)(row + r) * ldc + col] = acc[m][n][r] + bv;
        }
    }
}

// ---------------- QK^T: 256x128 tile, 8 waves (4Mx2N), dbuf BK=32 -----------
// 2 blocks/CU co-resident (grid 512): barrier drain of one block overlaps the
// other block's compute (m114 mechanism). q pre-scaled by scale*log2e.
__global__ __launch_bounds__(512, 4) void mgemm_qk_k(
    const unsigned short* __restrict__ A, const unsigned short* __restrict__ B,
    unsigned short* __restrict__ C, float* __restrict__ denom)
{
    constexpr int BK = 32;
    __shared__ unsigned short smem[24576];    // 48KB: 2 bufs x (A 16KB | B 8KB)
    const int t = threadIdx.x, lane = t & 63, w = t >> 6;   // 8 waves
    const int wr = w >> 1, wc = w & 1;        // 4 (M) x 2 (N)
    const int fr = lane & 15, fq = lane >> 4;
    const int bm = blockIdx.y * 256, bn = blockIdx.x * 128;

    f32x4 acc[4][4];
    #pragma unroll
    for (int m = 0; m < 4; m++)
        #pragma unroll
        for (int n = 0; n < 4; n++)
            #pragma unroll
            for (int r = 0; r < 4; r++) acc[m][n][r] = 0.f;

    auto stage = [&](int buf, int k0) {       // 3 gloads per thread
        unsigned short* dA = smem + buf * 12288;
        unsigned short* dB = dA + 8192;
        #pragma unroll
        for (int i = 0; i < 2; i++) {
            int s = i * 512 + t;              // 1024 slots = 256 rows x 4 cc
            int row = s >> 2, cc = s & 3;
            int gc = k0 + ((cc ^ (row & 3)) << 3);
            GLOAD16(A + (size_t)(bm + row) * 512 + gc, dA + (i * 512 + w * 64) * 8);
        }
        {
            int row = t >> 2, cc = t & 3;     // 512 slots = 128 rows x 4 cc
            int gc = k0 + ((cc ^ (row & 3)) << 3);
            GLOAD16(B + (size_t)(bn + row) * 512 + gc, dB + (size_t)t * 8);
        }
    };

    stage(0, 0);
    asm volatile("s_waitcnt vmcnt(0)" ::: "memory");
    __builtin_amdgcn_s_barrier();
    int cur = 0;
    for (int k0 = 0; k0 < 512; k0 += BK) {
        if (k0 + BK < 512) stage(cur ^ 1, k0 + BK);
        const unsigned short* rA = smem + cur * 12288;
        const unsigned short* rB = rA + 8192;
        s16x8 a[4], b[4];
        #pragma unroll
        for (int m = 0; m < 4; m++) {
            int row = wr * 64 + m * 16 + fr;
            a[m] = *(const s16x8*)&rA[row * BK + ((fq ^ (row & 3)) << 3)];
        }
        #pragma unroll
        for (int n = 0; n < 4; n++) {
            int row = wc * 64 + n * 16 + fr;
            b[n] = *(const s16x8*)&rB[row * BK + ((fq ^ (row & 3)) << 3)];
        }
        __builtin_amdgcn_s_setprio(1);
        #pragma unroll
        for (int m = 0; m < 4; m++)
            #pragma unroll
            for (int n = 0; n < 4; n++)
                acc[m][n] = __builtin_amdgcn_mfma_f32_16x16x32_bf16(a[m], b[n], acc[m][n], 0, 0, 0);
        __builtin_amdgcn_s_setprio(0);
        asm volatile("s_waitcnt vmcnt(0)" ::: "memory");
        __builtin_amdgcn_s_barrier();
        cur ^= 1;
    }

    // epilogue: exp2 + row-sum (atomic) + direct stores (32B runs)
    #pragma unroll
    for (int m = 0; m < 4; m++) {
        #pragma unroll
        for (int r = 0; r < 4; r++) {
            const int row = bm + wr * 64 + m * 16 + fq * 4 + r;   // chunk-local
            float rsum = 0.f;
            #pragma unroll
            for (int n = 0; n < 4; n++) {
                float p = exp2f(acc[m][n][r]);
                rsum += p;
                C[(size_t)row * 8192 + bn + wc * 64 + n * 16 + fr] = f2bf(p);
            }
            rsum += __shfl_xor(rsum, 1);
            rsum += __shfl_xor(rsum, 2);
            rsum += __shfl_xor(rsum, 4);
            rsum += __shfl_xor(rsum, 8);
            if (fr == 0) atomicAdd(&denom[row], rsum);
        }
    }
}

// ---------------- merged per-type input linear (dbuf BK=32) -----------------
template<bool SPLIT>
__global__ __launch_bounds__(256) void mgemm_in_k(
    const unsigned short* __restrict__ xA, const unsigned short* __restrict__ xB,
    const unsigned short* __restrict__ WA, const unsigned short* __restrict__ WB,
    const float* __restrict__ biasA, const float* __restrict__ biasB,
    unsigned short* __restrict__ o1, unsigned short* __restrict__ o2)
{
    constexpr int BK = 32;
    __shared__ unsigned short smem[16384];    // 32KB: 2 bufs x (A 8KB | W 8KB)
    const int t = threadIdx.x, lane = t & 63, w = t >> 6;
    const int wr = w >> 1, wc = w & 1;
    const int fr = lane & 15, fq = lane >> 4;
    const int bm = blockIdx.y * 128, bn = blockIdx.x * 128;
    const bool isB = bm >= NA_;
    const unsigned short* A = isB ? xB : xA;
    const unsigned short* W = isB ? WB : WA;
    const float* bias = isB ? biasB : biasA;
    const int bml = bm - (isB ? NA_ : 0);

    f32x4 acc[4][4];
    #pragma unroll
    for (int m = 0; m < 4; m++)
        #pragma unroll
        for (int n = 0; n < 4; n++)
            #pragma unroll
            for (int r = 0; r < 4; r++) acc[m][n][r] = 0.f;

    auto stage = [&](int buf, int k0) {
        unsigned short* dA = smem + buf * 8192;
        unsigned short* dB = dA + 4096;
        #pragma unroll
        for (int i = 0; i < 2; i++) {
            int s = i * 256 + t;              // 512 slots = 128 rows x 4 cc
            int row = s >> 2, cc = s & 3;
            int gc = k0 + ((cc ^ (row & 3)) << 3);
            GLOAD16(A + (size_t)(bml + row) * 256 + gc, dA + (i * 256 + w * 64) * 8);
            GLOAD16(W + (size_t)(bn + row) * 256 + gc, dB + (i * 256 + w * 64) * 8);
        }
    };

    stage(0, 0);
    asm volatile("s_waitcnt vmcnt(0)" ::: "memory");
    __builtin_amdgcn_s_barrier();
    int cur = 0;
    for (int k0 = 0; k0 < 256; k0 += BK) {
        if (k0 + BK < 256) stage(cur ^ 1, k0 + BK);
        const unsigned short* rA = smem + cur * 8192;
        const unsigned short* rB = rA + 4096;
        s16x8 a[4], b[4];
        #pragma unroll
        for (int m = 0; m < 4; m++) {
            int row = wr * 64 + m * 16 + fr;
            a[m] = *(const s16x8*)&rA[row * BK + ((fq ^ (row & 3)) << 3)];
        }
        #pragma unroll
        for (int n = 0; n < 4; n++) {
            int row = wc * 64 + n * 16 + fr;
            b[n] = *(const s16x8*)&rB[row * BK + ((fq ^ (row & 3)) << 3)];
        }
        __builtin_amdgcn_s_setprio(1);
        #pragma unroll
        for (int m = 0; m < 4; m++)
            #pragma unroll
            for (int n = 0; n < 4; n++)
                acc[m][n] = __builtin_amdgcn_mfma_f32_16x16x32_bf16(a[m], b[n], acc[m][n], 0, 0, 0);
        __builtin_amdgcn_s_setprio(0);
        asm volatile("s_waitcnt vmcnt(0)" ::: "memory");
        __builtin_amdgcn_s_barrier();
        cur ^= 1;
    }

    #pragma unroll
    for (int m = 0; m < 4; m++) {
        const int row = bm + wr * 64 + m * 16 + fq * 4;
        #pragma unroll
        for (int n = 0; n < 4; n++) {
            const int col = bn + wc * 64 + n * 16 + fr;
            const float bv = bias[col];
            #pragma unroll
            for (int r = 0; r < 4; r++) {
                float v = acc[m][n][r] + bv;
                unsigned short hi = f2bf(v);
                o1[(size_t)(row + r) * 512 + col] = hi;
                if (SPLIT)
                    o2[(size_t)(row + r) * 512 + col] = f2bf(v - bf2f(hi));
            }
        }
    }
}

// ---------------- split-A MFMA GEMM (2 MFMA), dbuf pipeline + fused dots ----
__global__ __launch_bounds__(256) void mgemm3_k(
    const unsigned short* __restrict__ Ahi, const unsigned short* __restrict__ Alo,
    const unsigned short* __restrict__ Bhi,
    unsigned short* __restrict__ Cb, const float* __restrict__ a_src,
    const float* __restrict__ a_dst, float* __restrict__ as_,
    float* __restrict__ ad_, int K, int lda, int ldb)
{
    constexpr int BK = 32;
    __shared__ unsigned short smem[24576];    // 48KB: 2 bufs x (Ah|Al|Bh) x 8KB
    const int t = threadIdx.x, lane = t & 63, w = t >> 6;
    const int wr = w >> 1, wc = w & 1;
    const int fr = lane & 15, fq = lane >> 4;
    const int bm = blockIdx.y * 128, bn = blockIdx.x * 128;

    f32x4 acc[4][4];
    #pragma unroll
    for (int m = 0; m < 4; m++)
        #pragma unroll
        for (int n = 0; n < 4; n++)
            #pragma unroll
            for (int r = 0; r < 4; r++) acc[m][n][r] = 0.f;

    auto stage = [&](int buf, int k0) {
        unsigned short* dAh = smem + buf * 12288;
        unsigned short* dAl = dAh + 4096;
        unsigned short* dBh = dAh + 8192;
        #pragma unroll
        for (int i = 0; i < 2; i++) {
            int s = i * 256 + t;              // 512 slots = 128 rows x 4 cc
            int row = s >> 2, cc = s & 3;
            int gco = (cc ^ (row & 3)) << 3;
            size_t ga = (size_t)(bm + row) * lda + k0 + gco;
            size_t gb = (size_t)(bn + row) * ldb + k0 + gco;
            unsigned loff = (unsigned)(i * 256 + w * 64) * 8;
            GLOAD16(Ahi + ga, dAh + loff);
            GLOAD16(Alo + ga, dAl + loff);
            GLOAD16(Bhi + gb, dBh + loff);
        }
    };

    stage(0, 0);
    asm volatile("s_waitcnt vmcnt(0)" ::: "memory");
    __builtin_amdgcn_s_barrier();
    int cur = 0;
    for (int k0 = 0; k0 < K; k0 += BK) {
        if (k0 + BK < K) stage(cur ^ 1, k0 + BK);
        const unsigned short* rAh = smem + cur * 12288;
        const unsigned short* rAl = rAh + 4096;
        const unsigned short* rBh = rAh + 8192;
        s16x8 ah[4], al[4], bh[4];
        #pragma unroll
        for (int m = 0; m < 4; m++) {
            int row = wr * 64 + m * 16 + fr;
            int o = row * BK + ((fq ^ (row & 3)) << 3);
            ah[m] = *(const s16x8*)&rAh[o];
            al[m] = *(const s16x8*)&rAl[o];
        }
        #pragma unroll
        for (int n = 0; n < 4; n++) {
            int row = wc * 64 + n * 16 + fr;
            bh[n] = *(const s16x8*)&rBh[row * BK + ((fq ^ (row & 3)) << 3)];
        }
        __builtin_amdgcn_s_setprio(1);
        #pragma unroll
        for (int m = 0; m < 4; m++)
            #pragma unroll
            for (int n = 0; n < 4; n++) {
                acc[m][n] = __builtin_amdgcn_mfma_f32_16x16x32_bf16(ah[m], bh[n], acc[m][n], 0, 0, 0);
                acc[m][n] = __builtin_amdgcn_mfma_f32_16x16x32_bf16(al[m], bh[n], acc[m][n], 0, 0, 0);
            }
        __builtin_amdgcn_s_setprio(0);
        asm volatile("s_waitcnt vmcnt(0)" ::: "memory");
        __builtin_amdgcn_s_barrier();
        cur ^= 1;
    }

    float asv[4], adv[4];
    #pragma unroll
    for (int n = 0; n < 4; n++) {
        const int col = bn + wc * 64 + n * 16 + fr;
        asv[n] = a_src[col];
        adv[n] = a_dst[col];
    }

    #pragma unroll
    for (int m = 0; m < 4; m++) {
        const int row = bm + wr * 64 + m * 16 + fq * 4;
        #pragma unroll
        for (int r = 0; r < 4; r++) {
            float s1 = 0.f, s2 = 0.f;
            #pragma unroll
            for (int n = 0; n < 4; n++) {
                const int col = bn + wc * 64 + n * 16 + fr;
                float v = acc[m][n][r];
                Cb[(size_t)(row + r) * 512 + col] = f2bf(v);
                s1 = fmaf(v, asv[n], s1);
                s2 = fmaf(v, adv[n], s2);
            }
            s1 += __shfl_xor(s1, 1); s2 += __shfl_xor(s2, 1);
            s1 += __shfl_xor(s1, 2); s2 += __shfl_xor(s2, 2);
            s1 += __shfl_xor(s1, 4); s2 += __shfl_xor(s2, 4);
            s1 += __shfl_xor(s1, 8); s2 += __shfl_xor(s2, 8);
            if (fr == 0) {
                atomicAdd(&as_[row + r], s1);
                atomicAdd(&ad_[row + r], s2);
            }
        }
    }
}

// ---------------- PV split-K: dbuf BK=32 pipeline, XCD swizzle --------------
__global__ __launch_bounds__(256) void mgemm_pv_k(
    const unsigned short* __restrict__ A, const unsigned short* __restrict__ B,
    unsigned short* __restrict__ C, int kseg, size_t segstride)
{
    constexpr int BK = 32;
    __shared__ unsigned short smem[16384];    // 32KB: 2 bufs x (A 8KB | B 8KB)
    const int t = threadIdx.x, lane = t & 63, w = t >> 6;
    const int wr = w >> 1, wc = w & 1;
    const int fr = lane & 15, fq = lane >> 4;
    const int L  = blockIdx.x + (blockIdx.y << 2) + (blockIdx.z << 6);
    const int xs = L >> 7;
    const int ys = (L & 127) & 15;
    const int zs = (L & 127) >> 4;
    const int bm = ys * 128, bn = xs * 128;
    const int kofs = zs * kseg;

    f32x4 acc[4][4];
    #pragma unroll
    for (int m = 0; m < 4; m++)
        #pragma unroll
        for (int n = 0; n < 4; n++)
            #pragma unroll
            for (int r = 0; r < 4; r++) acc[m][n][r] = 0.f;

    auto stage = [&](int buf, int k0) {
        unsigned short* dA = smem + buf * 8192;
        unsigned short* dB = dA + 4096;
        #pragma unroll
        for (int i = 0; i < 2; i++) {
            int s = i * 256 + t;              // 512 slots = 128 rows x 4 cc
            int row = s >> 2, cc = s & 3;
            int gc = kofs + k0 + ((cc ^ (row & 3)) << 3);
            GLOAD16(A + (size_t)(bm + row) * 8192 + gc, dA + (i * 256 + w * 64) * 8);
            GLOAD16(B + (size_t)(bn + row) * 8192 + gc, dB + (i * 256 + w * 64) * 8);
        }
    };

    stage(0, 0);
    asm volatile("s_waitcnt vmcnt(0)" ::: "memory");
    __builtin_amdgcn_s_barrier();
    int cur = 0;
    for (int k0 = 0; k0 < kseg; k0 += BK) {
        if (k0 + BK < kseg) stage(cur ^ 1, k0 + BK);
        const unsigned short* rA = smem + cur * 8192;
        const unsigned short* rB = rA + 4096;
        s16x8 a[4], b[4];
        #pragma unroll
        for (int m = 0; m < 4; m++) {
            int row = wr * 64 + m * 16 + fr;
            a[m] = *(const s16x8*)&rA[row * BK + ((fq ^ (row & 3)) << 3)];
        }
        #pragma unroll
        for (int n = 0; n < 4; n++) {
            int row = wc * 64 + n * 16 + fr;
            b[n] = *(const s16x8*)&rB[row * BK + ((fq ^ (row & 3)) << 3)];
        }
        __builtin_amdgcn_s_setprio(1);
        #pragma unroll
        for (int m = 0; m < 4; m++)
            #pragma unroll
            for (int n = 0; n < 4; n++)
                acc[m][n] = __builtin_amdgcn_mfma_f32_16x16x32_bf16(a[m], b[n], acc[m][n], 0, 0, 0);
        __builtin_amdgcn_s_setprio(0);
        asm volatile("s_waitcnt vmcnt(0)" ::: "memory");
        __builtin_amdgcn_s_barrier();
        cur ^= 1;
    }

    unsigned short* Cz = C + (size_t)zs * segstride;
    #pragma unroll
    for (int m = 0; m < 4; m++) {
        const int row = bm + wr * 64 + m * 16 + fq * 4;
        #pragma unroll
        for (int n = 0; n < 4; n++) {
            const int col = bn + wc * 64 + n * 16 + fr;
            #pragma unroll
            for (int r = 0; r < 4; r++)
                Cz[(size_t)(row + r) * 512 + col] = f2bf(acc[m][n][r]);
        }
    }
}

// ---------------- reduce bf16 split-K partials, divide by denom -> bf16 ----
__global__ __launch_bounds__(256) void radd_k(const unsigned short* __restrict__ src,
                                              unsigned short* __restrict__ dst,
                                              const float* __restrict__ dn,
                                              int n8, int segs, size_t stride8) {
    int i = blockIdx.x * 256 + threadIdx.x;
    if (i >= n8) return;
    float acc[8] = {0,0,0,0,0,0,0,0};
    for (int s = 0; s < segs; s++) {
        s16x8 v = ((const s16x8*)src)[i + s * stride8];
        #pragma unroll
        for (int j = 0; j < 8; j++) acc[j] += bf2f((unsigned short)v[j]);
    }
    const float rd = 1.0f / dn[i >> 6];    // 64 groups of 8 per 512-col row
    s16x8 o;
    #pragma unroll
    for (int j = 0; j < 8; j++) o[j] = (short)f2bf(acc[j] * rd);
    ((s16x8*)dst)[i] = o;
}

// ---------------- qkv GEMM, dbuf pipeline, split epilogue (scale in q) ------
__global__ __launch_bounds__(256) void mgemm_qkv_k(
    const unsigned short* __restrict__ A, const unsigned short* __restrict__ B,
    const float* __restrict__ bias, float scale,
    unsigned short* __restrict__ qb, unsigned short* __restrict__ kb,
    unsigned short* __restrict__ vb)
{
    constexpr int BK = 32;
    __shared__ unsigned short smem[16384];    // 32KB: 2 bufs x (A 8KB | B 8KB)
    const int t = threadIdx.x, lane = t & 63, w = t >> 6;
    const int wr = w >> 1, wc = w & 1;
    const int fr = lane & 15, fq = lane >> 4;
    const int bm = blockIdx.y * 128, bn = blockIdx.x * 128;

    f32x4 acc[4][4];
    #pragma unroll
    for (int m = 0; m < 4; m++)
        #pragma unroll
        for (int n = 0; n < 4; n++)
            #pragma unroll
            for (int r = 0; r < 4; r++) acc[m][n][r] = 0.f;

    auto stage = [&](int buf, int k0) {
        unsigned short* dA = smem + buf * 8192;
        unsigned short* dB = dA + 4096;
        #pragma unroll
        for (int i = 0; i < 2; i++) {
            int s = i * 256 + t;              // 512 slots = 128 rows x 4 cc
            int row = s >> 2, cc = s & 3;
            int gc = k0 + ((cc ^ (row & 3)) << 3);
            GLOAD16(A + (size_t)(bm + row) * 512 + gc, dA + (i * 256 + w * 64) * 8);
            GLOAD16(B + (size_t)(bn + row) * 512 + gc, dB + (i * 256 + w * 64) * 8);
        }
    };

    stage(0, 0);
    asm volatile("s_waitcnt vmcnt(0)" ::: "memory");
    __builtin_amdgcn_s_barrier();
    int cur = 0;
    for (int k0 = 0; k0 < 512; k0 += BK) {
        if (k0 + BK < 512) stage(cur ^ 1, k0 + BK);
        const unsigned short* rA = smem + cur * 8192;
        const unsigned short* rB = rA + 4096;
        s16x8 a[4], b[4];
        #pragma unroll
        for (int m = 0; m < 4; m++) {
            int row = wr * 64 + m * 16 + fr;
            a[m] = *(const s16x8*)&rA[row * BK + ((fq ^ (row & 3)) << 3)];
        }
        #pragma unroll
        for (int n = 0; n < 4; n++) {
            int row = wc * 64 + n * 16 + fr;
            b[n] = *(const s16x8*)&rB[row * BK + ((fq ^ (row & 3)) << 3)];
        }
        __builtin_amdgcn_s_setprio(1);
        #pragma unroll
        for (int m = 0; m < 4; m++)
            #pragma unroll
            for (int n = 0; n < 4; n++)
                acc[m][n] = __builtin_amdgcn_mfma_f32_16x16x32_bf16(a[m], b[n], acc[m][n], 0, 0, 0);
        __builtin_amdgcn_s_setprio(0);
        asm volatile("s_waitcnt vmcnt(0)" ::: "memory");
        __builtin_amdgcn_s_barrier();
        cur ^= 1;
    }

    #pragma unroll
    for (int m = 0; m < 4; m++) {
        const int row = bm + wr * 64 + m * 16 + fq * 4;
        #pragma unroll
        for (int n = 0; n < 4; n++) {
            const int col = bn + wc * 64 + n * 16 + fr;
            const float bv = bias[col];
            #pragma unroll
            for (int r = 0; r < 4; r++) {
                float v = acc[m][n][r] + bv;
                if (col < 512)
                    qb[(size_t)(row + r) * 512 + col] = f2bf(v * scale);
                else if (col < 1024)
                    kb[(size_t)(row + r) * 512 + (col - 512)] = f2bf(v);
                else
                    vb[(size_t)(row + r) * 512 + (col - 1024)] = f2bf(v);
            }
        }
    }
}

// ---------------- bf16 transpose: vb[8192][512] -> vT[512][8192] ------------
__global__ __launch_bounds__(256) void trT_k(const unsigned short* __restrict__ vb,
                                             unsigned short* __restrict__ vT) {
    __shared__ unsigned short s[64][65];
    const int t = threadIdx.x;
    const int rowo = blockIdx.y * 64;
    const int colo = blockIdx.x * 64;
    {
        int r = t >> 2, cg = (t & 3) * 16;
        const s16x8* src = (const s16x8*)(vb + (size_t)(rowo + r) * 512 + colo + cg);
        s16x8 u0 = src[0], u1 = src[1];
        #pragma unroll
        for (int j = 0; j < 8; j++) {
            s[r][cg + j]     = (unsigned short)u0[j];
            s[r][cg + 8 + j] = (unsigned short)u1[j];
        }
    }
    __syncthreads();
    {
        int c = t >> 2, rg = (t & 3) * 16;
        s16x8 o0, o1;
        #pragma unroll
        for (int j = 0; j < 8; j++) {
            o0[j] = (short)s[rg + j][c];
            o1[j] = (short)s[rg + 8 + j][c];
        }
        s16x8* dst = (s16x8*)(vT + (size_t)(colo + c) * 8192 + rowo + rg);
        dst[0] = o0; dst[1] = o1;
    }
}

// ---------------- CSR build ------------------------------------------------
__global__ void count_deg_k(const int* eAB, const int* eBA, int* deg) {
    int i = blockIdx.x * 256 + threadIdx.x;
    if (i >= NE_) return;
    int s, d; edge_sd(i, eAB, eBA, s, d);
    atomicAdd(&deg[d], 1);
}

__global__ __launch_bounds__(256) void scan_k(const int* __restrict__ deg, int* rowstart) {
    __shared__ int part[256];
    int t = threadIdx.x;
    int base = t * 32;
    int loc[32]; int s = 0;
    #pragma unroll
    for (int j = 0; j < 32; j++) { loc[j] = s; s += deg[base + j]; }
    part[t] = s;
    __syncthreads();
    if (t == 0) {
        int a = 0;
        for (int i = 0; i < 256; i++) { int v = part[i]; part[i] = a; a += v; }
        rowstart[NN_] = a;
    }
    __syncthreads();
    int off = part[t];
    #pragma unroll
    for (int j = 0; j < 32; j++) rowstart[base + j] = off + loc[j];
}

__global__ void fill_csr_k(const int* eAB, const int* eBA,
                           const int* __restrict__ rowstart, int* cursor,
                           int* csr_src, int* pos) {
    int i = blockIdx.x * 256 + threadIdx.x;
    if (i >= NE_) return;
    int s, d; edge_sd(i, eAB, eBA, s, d);
    int p = atomicAdd(&cursor[d], 1);
    int slot = rowstart[d] + p;
    csr_src[slot] = s;
    pos[i] = slot;
}

// ---------------- fused GAT edge pass: e -> exp(e) scatter + denom ----------
__global__ void edge_fused_k(const int* eAB, const int* eBA,
                             const float* __restrict__ as_, const float* __restrict__ ad_,
                             const int* __restrict__ pos,
                             float* __restrict__ evs, float* __restrict__ denom) {
    int i = blockIdx.x * 256 + threadIdx.x;
    if (i >= NE_) return;
    int s, d; edge_sd(i, eAB, eBA, s, d);
    float e = as_[s] + ad_[d];
    e = (e >= 0.f) ? e : NEG_SLOPE_ * e;
    float ex = expf(e);
    evs[pos[i]] = ex;
    atomicAdd(&denom[d], ex);
}

// ---------------- GAT aggregation: streaming CSR, 4-edge unrolled -----------
template<bool SPLIT>
__global__ __launch_bounds__(256) void gat_agg_k(
    const int* __restrict__ rowstart, const int* __restrict__ csr_src,
    const float* __restrict__ evs, const float* __restrict__ denom,
    const unsigned short* __restrict__ hb, const float* __restrict__ bias,
    float* __restrict__ outF, int ldo,
    unsigned short* __restrict__ outHi, unsigned short* __restrict__ outLo)
{
    int wid  = (blockIdx.x * 256 + threadIdx.x) >> 6;
    int lane = threadIdx.x & 63;
    if (wid >= NN_) return;
    float acc[8] = {0.f,0.f,0.f,0.f,0.f,0.f,0.f,0.f};
    int beg = rowstart[wid], end = rowstart[wid + 1];
    float rden = 1.0f / denom[wid];
    int p = beg;
    for (; p + 3 < end; p += 4) {
        int s0 = csr_src[p],     s1 = csr_src[p + 1];
        int s2 = csr_src[p + 2], s3 = csr_src[p + 3];
        float al0 = evs[p] * rden,     al1 = evs[p + 1] * rden;
        float al2 = evs[p + 2] * rden, al3 = evs[p + 3] * rden;
        s16x8 h0 = *(const s16x8*)(hb + (size_t)s0 * HH_ + lane * 8);
        s16x8 h1 = *(const s16x8*)(hb + (size_t)s1 * HH_ + lane * 8);
        s16x8 h2 = *(const s16x8*)(hb + (size_t)s2 * HH_ + lane * 8);
        s16x8 h3 = *(const s16x8*)(hb + (size_t)s3 * HH_ + lane * 8);
        #pragma unroll
        for (int j = 0; j < 8; j++) {
            float x = fmaf(al0, bf2f((unsigned short)h0[j]),
                      fmaf(al1, bf2f((unsigned short)h1[j]), acc[j]));
            acc[j] = fmaf(al2, bf2f((unsigned short)h2[j]),
                     fmaf(al3, bf2f((unsigned short)h3[j]), x));
        }
    }
    for (; p < end; p++) {
        int s0 = csr_src[p];
        float al0 = evs[p] * rden;
        s16x8 h0 = *(const s16x8*)(hb + (size_t)s0 * HH_ + lane * 8);
        #pragma unroll
        for (int j = 0; j < 8; j++)
            acc[j] = fmaf(al0, bf2f((unsigned short)h0[j]), acc[j]);
    }
    #pragma unroll
    for (int j = 0; j < 8; j++) acc[j] += bias[lane * 8 + j];
    if (SPLIT) {
        s16x8 hi, lo;
        #pragma unroll
        for (int j = 0; j < 8; j++) {
            unsigned short h = f2bf(acc[j]);
            hi[j] = (short)h;
            lo[j] = (short)f2bf(acc[j] - bf2f(h));
        }
        *(s16x8*)(outHi + (size_t)wid * HH_ + lane * 8) = hi;
        *(s16x8*)(outLo + (size_t)wid * HH_ + lane * 8) = lo;
    } else {
        float* o = outF + (size_t)wid * ldo + lane * 8;
        *(float4*)(o)     = make_float4(acc[0], acc[1], acc[2], acc[3]);
        *(float4*)(o + 4) = make_float4(acc[4], acc[5], acc[6], acc[7]);
    }
}

// ===========================================================================
extern "C" void kernel_launch(void* const* d_in, const int* in_sizes, int n_in,
                              void* d_out, int out_size, void* d_ws, size_t ws_size,
                              hipStream_t stream)
{
    const float* x_A    = (const float*)d_in[0];
    const float* x_B    = (const float*)d_in[1];
    const int*   eAB    = (const int*)d_in[2];
    const int*   eBA    = (const int*)d_in[3];
    const float* W_inA  = (const float*)d_in[4];  const float* b_inA  = (const float*)d_in[5];
    const float* W_inB  = (const float*)d_in[6];  const float* b_inB  = (const float*)d_in[7];
    const float* W_in2A = (const float*)d_in[8];  const float* b_in2A = (const float*)d_in[9];
    const float* W_in2B = (const float*)d_in[10]; const float* b_in2B = (const float*)d_in[11];
    const float* Wg1    = (const float*)d_in[12]; const float* a_src1 = (const float*)d_in[13];
    const float* a_dst1 = (const float*)d_in[14]; const float* bg1    = (const float*)d_in[15];
    const float* Wg2    = (const float*)d_in[16]; const float* a_src2 = (const float*)d_in[17];
    const float* a_dst2 = (const float*)d_in[18]; const float* bg2    = (const float*)d_in[19];
    const float* Wqkv   = (const float*)d_in[20]; const float* bqkv   = (const float*)d_in[21];
    const float* Wo     = (const float*)d_in[22]; const float* bo     = (const float*)d_in[23];

    float* out = (float*)d_out;

    char* base = (char*)d_ws;
    size_t off = 0;
    auto alloc = [&](size_t nb) -> char* {
        char* p = base + off;
        off = (off + nb + 255) & ~(size_t)255;
        return p;
    };

    // bufA and bufB MUST be adjacent: Sb (32MB) spans both during attention.
    float*          bufA  = (float*)alloc((size_t)NN_ * 512 * 4);
    float*          bufB  = (float*)alloc((size_t)NN_ * 512 * 4);
    float*          bufC  = (float*)alloc((size_t)NN_ * 512 * 4);
    // as_..cdn contiguous: first memset covers all six; re-zero covers first 3
    float*          as_   = (float*)alloc(NN_ * 4);
    float*          ad_   = (float*)alloc(NN_ * 4);
    float*          denom = (float*)alloc(NN_ * 4);
    int*            deg   = (int*)alloc(NN_ * 4);
    int*            cursor= (int*)alloc(NN_ * 4);
    float*          cdn   = (float*)alloc(NN_ * 4);    // per-chunk attn denoms
    int*            rowst = (int*)alloc((NN_ + 1) * 4);
    int*            csrs  = (int*)alloc((size_t)NE_ * 4);   // src per CSR slot
    int*            pos   = (int*)alloc((size_t)NE_ * 4);   // edge -> CSR slot
    float*          evs   = (float*)alloc((size_t)NE_ * 4); // exp in CSR order
    unsigned short* xbA   = (unsigned short*)alloc((size_t)NA_ * 256 * 2);
    unsigned short* xbB   = (unsigned short*)alloc((size_t)NB_ * 256 * 2);
    unsigned short* WbinA = (unsigned short*)alloc((size_t)512 * 256 * 2);
    unsigned short* WbinB = (unsigned short*)alloc((size_t)512 * 256 * 2);
    unsigned short* Wbin2A= (unsigned short*)alloc((size_t)512 * 256 * 2);
    unsigned short* Wbin2B= (unsigned short*)alloc((size_t)512 * 256 * 2);
    unsigned short* Wbqkv = (unsigned short*)alloc((size_t)1536 * 512 * 2);
    unsigned short* Wbo   = (unsigned short*)alloc((size_t)512 * 512 * 2);
    unsigned short* Wg1b  = (unsigned short*)alloc((size_t)512 * 512 * 2);
    unsigned short* Wg2b  = (unsigned short*)alloc((size_t)512 * 512 * 2);
    unsigned short* qb    = (unsigned short*)alloc((size_t)NN_ * 512 * 2);
    unsigned short* kb    = (unsigned short*)alloc((size_t)NN_ * 512 * 2);
    unsigned short* vT    = (unsigned short*)alloc((size_t)512 * NN_ * 2);
    unsigned short* ab    = (unsigned short*)alloc((size_t)NN_ * 512 * 2);

    // overlays
    unsigned short* hb = vT;                              // bf16 h (local branch)
    unsigned short* gb = (unsigned short*)bufC;           // g bf16 (global, pre-loop)
    unsigned short* vb = gb + (size_t)NN_ * 512;          // v bf16 (global, pre-loop)
    unsigned short* Sb = (unsigned short*)bufA;           // scores: bufA+bufB = 32MB
    unsigned short* pv = (unsigned short*)bufC;           // PV bf16 partials (16MB)

    const int R = 2048, SEGS = 8, KSEG = 8192 / SEGS;
    const int EG = (NE_ + 255) / 256;
    const float scale2 = 0.044194173824159216f * 1.4426950408889634f; // /sqrt(512)*log2e

    // -------- all weight/input casts in ONE launch --------------------------
    CvtJobs jobs;
    jobs.j[0] = { x_A,    xbA,    nullptr, NA_ * 256 / 4 };
    jobs.j[1] = { x_B,    xbB,    nullptr, NB_ * 256 / 4 };
    jobs.j[2] = { W_inA,  WbinA,  nullptr, 512 * 256 / 4 };
    jobs.j[3] = { W_inB,  WbinB,  nullptr, 512 * 256 / 4 };
    jobs.j[4] = { W_in2A, Wbin2A, nullptr, 512 * 256 / 4 };
    jobs.j[5] = { W_in2B, Wbin2B, nullptr, 512 * 256 / 4 };
    jobs.j[6] = { Wqkv,   Wbqkv,  nullptr, 1536 * 512 / 4 };
    jobs.j[7] = { Wo,     Wbo,    nullptr, 512 * 512 / 4 };
    jobs.j[8] = { Wg1,    Wg1b,   nullptr, 512 * 512 / 4 };
    jobs.j[9] = { Wg2,    Wg2b,   nullptr, 512 * 512 / 4 };
    cvt_all_k<<<dim3(NA_ * 256 / 4 / 256, 10), 256, 0, stream>>>(jobs);

    // zero as_, ad_, denom, deg, cursor, cdn in one shot
    hipMemsetAsync(as_, 0, (size_t)NN_ * 4 * 6, stream);

    // -------- CSR build -----------------------------------------------------
    count_deg_k<<<EG, 256, 0, stream>>>(eAB, eBA, deg);
    scan_k<<<1, 256, 0, stream>>>(deg, rowst);
    fill_csr_k<<<EG, 256, 0, stream>>>(eAB, eBA, rowst, cursor, csrs, pos);

    // -------- local branch --------------------------------------------------
    mgemm_in_k<true><<<dim3(4, 64), 256, 0, stream>>>(
        xbA, xbB, WbinA, WbinB, b_inA, b_inB, qb, kb);
    mgemm3_k<<<dim3(4, 64), 256, 0, stream>>>(qb, kb, Wg1b,
                                              hb, a_src1, a_dst1, as_, ad_,
                                              512, 512, 512);
    edge_fused_k<<<EG, 256, 0, stream>>>(eAB, eBA, as_, ad_, pos, evs, denom);
    gat_agg_k<true><<<NN_/4, 256, 0, stream>>>(rowst, csrs, evs, denom,
                                               hb, bg1, nullptr, 0, qb, kb);
    hipMemsetAsync(as_, 0, NN_ * 12, stream);           // as_, ad_, denom
    mgemm3_k<<<dim3(4, 64), 256, 0, stream>>>(qb, kb, Wg2b,
                                              hb, a_src2, a_dst2, as_, ad_,
                                              512, 512, 512);
    edge_fused_k<<<EG, 256, 0, stream>>>(eAB, eBA, as_, ad_, pos, evs, denom);
    // layer-2 aggregation writes the local half of d_out directly (ldo=1024)
    gat_agg_k<false><<<NN_/4, 256, 0, stream>>>(rowst, csrs, evs, denom,
                                                hb, bg2, out, 1024, nullptr, nullptr);

    // -------- global branch -------------------------------------------------
    mgemm_in_k<false><<<dim3(4, 64), 256, 0, stream>>>(
        xbA, xbB, Wbin2A, Wbin2B, b_in2A, b_in2B, gb, nullptr);
    mgemm_qkv_k<<<dim3(12, 64), 256, 0, stream>>>(gb, Wbqkv, bqkv, scale2, qb, kb, vb);
    trT_k<<<dim3(8, 128), 256, 0, stream>>>(vb, vT);
    for (int c0 = 0; c0 < 8192; c0 += R) {
        float* dn = cdn + c0;   // this chunk's 2048 denominators (pre-zeroed)
        mgemm_qk_k<<<dim3(64, 8), 512, 0, stream>>>(
            qb + (size_t)c0 * 512, kb, Sb, dn);
        mgemm_pv_k<<<dim3(4, R/128, SEGS), 256, 0, stream>>>(
            Sb, vT, pv, KSEG, (size_t)R * 512);
        radd_k<<<(R*512/8 + 255)/256, 256, 0, stream>>>(
            pv, ab + (size_t)c0 * 512, dn, R*512/8, SEGS, (size_t)R*512/8);
    }
    // Wo GEMM writes the global half of d_out directly (ldc=1024, col offset 512)
    mgemm_wo_k<<<dim3(4, 64), 256, 0, stream>>>(ab, Wbo, bo, out + 512, 1024);
}